// Round 9
// baseline (13743.027 us; speedup 1.0000x reference)
//
#include <hip/hip_runtime.h>
#include <hip/hip_bf16.h>
#include <math.h>

#define SE_    128
#define T_     256
#define B_     128
#define NH_    4
#define HD_    132
#define D_MODEL_ 528
#define D_FINAL_ 1040
#define D_FF_  128

typedef __hip_bfloat16 bf16;
typedef __attribute__((ext_vector_type(8))) short bf16x8v;
typedef __attribute__((ext_vector_type(4))) float f32x4;

__device__ __forceinline__ float bfb(unsigned short u){
  union { float f; unsigned int i; } c; c.i = ((unsigned int)u) << 16; return c.f;
}
__device__ __forceinline__ unsigned short bfr(float x){
  unsigned u = __builtin_bit_cast(unsigned, x);
  unsigned r = (u + 0x7FFFu + ((u >> 16) & 1u)) >> 16;
  return (unsigned short)r;
}
__device__ __forceinline__ void split1(float x, short& h, short& l){
  const unsigned short hu = bfr(x);
  const unsigned short lu = bfr(x - bfb(hu));
  h = (short)hu; l = (short)lu;
}
__device__ __forceinline__ float prd(const short* p, long i, long lo){
  return bfb((unsigned short)p[i]) + bfb((unsigned short)p[i+lo]);
}
__device__ __forceinline__ float rdIn(const void* p, long i, int f32){
  return f32 ? ((const float*)p)[i] : __bfloat162float(((const bf16*)p)[i]);
}

// ---------------- dtype detect: 1 = f32 inputs, 0 = bf16 ----------------
__global__ void detect_k(const void* __restrict__ src, int* __restrict__ flag){
  const unsigned int* p = (const unsigned int*)src;
  int bad = 0;
  for (int i = threadIdx.x; i < 4096; i += 256){
    const unsigned int lo = p[i] & 0xFFFFu;
    const unsigned int e = (lo >> 7) & 0xFFu;
    if (e >= 0xC0u) bad++;
  }
  __shared__ int red[256];
  red[threadIdx.x] = bad; __syncthreads();
  for (int h = 128; h > 0; h >>= 1){
    if (threadIdx.x < h) red[threadIdx.x] += red[threadIdx.x+h];
    __syncthreads();
  }
  if (threadIdx.x == 0) *flag = (red[0] > 64) ? 1 : 0;
}

// ---------------- mega conversion: all weights -> hi/lo bf16 planes ----------------
#define MAXE 40
struct CvtTab {
  const void* src[MAXE];
  long srcOff[MAXE];
  long dstOff[MAXE];
  int n[MAXE];
  int bstart[MAXE];
  int cnt;
};
__global__ void cvt_all(CvtTab tb, short* __restrict__ wts, long loW, const int* __restrict__ flag){
  const int b = blockIdx.x;
  int e = 0;
  for (int i = 1; i < tb.cnt; ++i) if (tb.bstart[i] <= b) e = i;
  const long i = (long)(b - tb.bstart[e])*256 + threadIdx.x;
  if (i >= tb.n[e]) return;
  const float v = rdIn(tb.src[e], tb.srcOff[e] + i, *flag);
  short h, l; split1(v, h, l);
  wts[tb.dstOff[e] + i] = h;
  wts[tb.dstOff[e] + i + loW] = l;
}

// ---------------- A K-tile register loads (prefetchable) ----------------
struct RegsP { int4 v[4]; };   // [0..1]=hi 16 shorts, [2..3]=lo

template<bool A16>
__device__ __forceinline__ void ld_pair(const short* __restrict__ P, long lo, long ld,
                                        int kb, int K, int g, bool valid, int sc0, RegsP& r){
  short* a = (short*)r.v;
  const int k0 = kb + sc0;
  const short* ph = P + (long)g*ld + k0;
  if (valid && (k0 + 16 <= K)){
    if (A16){
      r.v[0] = *(const int4*)(ph);
      r.v[1] = *(const int4*)(ph + 8);
      r.v[2] = *(const int4*)(ph + lo);
      r.v[3] = *(const int4*)(ph + lo + 8);
    } else {
      #pragma unroll
      for (int q=0;q<4;++q){
        *(int2*)(a + q*4)      = *(const int2*)(ph + q*4);
        *(int2*)(a + 16 + q*4) = *(const int2*)(ph + lo + q*4);
      }
    }
  } else {
    #pragma unroll
    for (int e2=0;e2<16;++e2){
      const bool ok = valid && (k0 + e2 < K);
      a[e2]    = ok ? ph[e2] : (short)0;
      a[16+e2] = ok ? ph[lo + e2] : (short)0;
    }
  }
}

__device__ __forceinline__ void ld_f32(const float* __restrict__ P, long ld, int kb, int K,
                                       int g, bool valid, int sc0, float* f){
  const int k0 = kb + sc0;
  const float* p = P + (long)g*ld + k0;
  if (valid && (k0 + 16 <= K)){
    #pragma unroll
    for (int q=0;q<4;++q) *(float4*)(f+q*4) = *(const float4*)(p + q*4);
  } else {
    #pragma unroll
    for (int e2=0;e2<16;++e2) f[e2] = (valid && (k0+e2) < K) ? p[e2] : 0.f;
  }
}

__device__ __forceinline__ void wr_pair(const RegsP& r, short* Lh, short* Ll, int srow, int sc0){
  *(int4*)(&Lh[srow*40 + sc0])     = r.v[0];
  *(int4*)(&Lh[srow*40 + sc0 + 8]) = r.v[1];
  *(int4*)(&Ll[srow*40 + sc0])     = r.v[2];
  *(int4*)(&Ll[srow*40 + sc0 + 8]) = r.v[3];
}
__device__ __forceinline__ void wr_split(const float* f, short* Lh, short* Ll, int srow, int sc0){
  short h[16], l[16];
  #pragma unroll
  for (int e2=0;e2<16;++e2) split1(f[e2], h[e2], l[e2]);
  *(int4*)(&Lh[srow*40+sc0])   = *(const int4*)(h);
  *(int4*)(&Lh[srow*40+sc0+8]) = *(const int4*)(h+8);
  *(int4*)(&Ll[srow*40+sc0])   = *(const int4*)(l);
  *(int4*)(&Ll[srow*40+sc0+8]) = *(const int4*)(l+8);
}

// ---------------- direct-to-register B MFMA fragments ----------------
// lane (n = base + j*16 + fr, k = kb + kq .. +7): 16B contiguous global load.
// DB=16: int4 loads (base 16B-aligned). DB=8: int2 pairs (8B-aligned).
template<int DB>
__device__ __forceinline__ void ldB_frag(const short* __restrict__ Bf, long lo, long ldb,
                                         int kb, int K, int N, int nbase, int fr, int kq,
                                         int4 bh[4], int4 bl[4]){
  const int k0 = kb + kq;
  #pragma unroll
  for (int j=0;j<4;++j){
    int gn = nbase + j*16 + fr;
    if (gn >= N) gn = N-1;                 // clamped rows feed discarded C cols
    const short* p = Bf + (long)gn*ldb + k0;
    if (k0 + 8 <= K){
      if (DB == 16){
        bh[j] = *(const int4*)(p);
        bl[j] = *(const int4*)(p + lo);
      } else {
        int2* h2 = (int2*)&bh[j]; int2* l2 = (int2*)&bl[j];
        h2[0] = *(const int2*)(p);      h2[1] = *(const int2*)(p + 4);
        l2[0] = *(const int2*)(p + lo); l2[1] = *(const int2*)(p + lo + 4);
      }
    } else {
      short* hs = (short*)&bh[j]; short* ls = (short*)&bl[j];
      #pragma unroll
      for (int e=0;e<8;++e){
        const bool ok = (k0 + e) < K;
        hs[e] = ok ? p[e] : (short)0;
        ls[e] = ok ? p[lo + e] : (short)0;
      }
    }
  }
}

// =======================================================================
// bf16x3 emulated-f32 NT GEMM: A via LDS, B direct-to-register (prefetched),
// pair-plane operands, routed pair epilogue.
// =======================================================================
struct Route { short* C; long ldc; long lo; long sC; long sC2; int nEnd; int fl; }; // fl: 1=trans 2=acc

template<bool SPLITA, bool A16, int DB>
__global__ __launch_bounds__(256) void gemm_s(
    const void* __restrict__ Ag, long loA,
    const short* __restrict__ Bg, long loB,
    const short* __restrict__ bias, long loBias,
    int M, int N, int K, long lda, long ldb,
    int nz1, long sA, long sB, long sA2, long sB2,
    int relu, int nroute, Route r0, Route r1, Route r2, float mult)
{
  __shared__ short As_h[128*40], As_l[128*40];
  const int tid = threadIdx.x;
  const int z1 = blockIdx.z % nz1, z2 = blockIdx.z / nz1;
  const int m0 = blockIdx.y*128, n0 = blockIdx.x*128;
  const void* A;
  if (SPLITA) A = (const void*)((const float*)Ag + z1*sA + z2*sA2);
  else        A = (const void*)((const short*)Ag + z1*sA + z2*sA2);
  const short* B = Bg + z1*sB + z2*sB2;
  short* Cb0 = r0.C + z1*r0.sC + z2*r0.sC2;
  short* Cb1 = (nroute > 1) ? (r1.C + z1*r1.sC + z2*r1.sC2) : nullptr;
  short* Cb2 = (nroute > 2) ? (r2.C + z1*r2.sC + z2*r2.sC2) : nullptr;

  const int srow = tid >> 1, sc0 = (tid & 1)*16;
  const int lane = tid & 63, wv = tid >> 6;
  const int wm = (wv >> 1)*64, wn = (wv & 1)*64;
  const int fr = lane & 15, kq = (lane >> 4)*8;

  const int gm_s = m0 + srow; const bool mval = gm_s < M;

  RegsP rA; float fA[16];
  if (SPLITA) ld_f32((const float*)A, lda, 0, K, gm_s, mval, sc0, fA);
  else        ld_pair<A16>((const short*)A, loA, lda, 0, K, gm_s, mval, sc0, rA);
  int4 bhv[2][4], blv[2][4];
  ldB_frag<DB>(B, loB, ldb, 0, K, N, n0+wn, fr, kq, bhv[0], blv[0]);

  f32x4 acc[4][4] = {};
  int p = 0;
  for (int kb = 0; kb < K; kb += 32, p ^= 1){
    if (SPLITA) wr_split(fA, As_h, As_l, srow, sc0);
    else        wr_pair(rA, As_h, As_l, srow, sc0);
    __syncthreads();
    const int kn = kb + 32;
    if (kn < K){
      if (SPLITA) ld_f32((const float*)A, lda, kn, K, gm_s, mval, sc0, fA);
      else        ld_pair<A16>((const short*)A, loA, lda, kn, K, gm_s, mval, sc0, rA);
      ldB_frag<DB>(B, loB, ldb, kn, K, N, n0+wn, fr, kq, bhv[p^1], blv[p^1]);
    }
    bf16x8v ah[4], al[4];
    #pragma unroll
    for (int i=0;i<4;++i){
      ah[i] = *reinterpret_cast<const bf16x8v*>(&As_h[(wm + i*16 + fr)*40 + kq]);
      al[i] = *reinterpret_cast<const bf16x8v*>(&As_l[(wm + i*16 + fr)*40 + kq]);
    }
    #pragma unroll
    for (int i=0;i<4;++i)
      #pragma unroll
      for (int j=0;j<4;++j){
        const bf16x8v bh = __builtin_bit_cast(bf16x8v, bhv[p][j]);
        const bf16x8v bl = __builtin_bit_cast(bf16x8v, blv[p][j]);
        acc[i][j] = __builtin_amdgcn_mfma_f32_16x16x32_bf16(ah[i], bh, acc[i][j], 0,0,0);
        acc[i][j] = __builtin_amdgcn_mfma_f32_16x16x32_bf16(ah[i], bl, acc[i][j], 0,0,0);
        acc[i][j] = __builtin_amdgcn_mfma_f32_16x16x32_bf16(al[i], bh, acc[i][j], 0,0,0);
      }
    __syncthreads();
  }

  const int cr = (lane >> 4)*4, cc = lane & 15;
  #pragma unroll
  for (int i=0;i<4;++i){
    #pragma unroll
    for (int j=0;j<4;++j){
      #pragma unroll
      for (int rr=0;rr<4;++rr){
        const int gm = m0 + wm + i*16 + cr + rr;
        const int gn = n0 + wn + j*16 + cc;
        if (gm < M && gn < N){
          float v = acc[i][j][rr] * mult;
          if (bias) v += prd(bias, gn, loBias);
          if (relu) v = fmaxf(v, 0.f);
          short* Cp; long ldc, lo; int fl, cn;
          if (nroute > 1 && gn >= r0.nEnd){
            if (nroute > 2 && gn >= r1.nEnd){ Cp=Cb2; ldc=r2.ldc; lo=r2.lo; fl=r2.fl; cn=gn-r1.nEnd; }
            else                            { Cp=Cb1; ldc=r1.ldc; lo=r1.lo; fl=r1.fl; cn=gn-r0.nEnd; }
          } else                            { Cp=Cb0; ldc=r0.ldc; lo=r0.lo; fl=r0.fl; cn=gn; }
          const long idx = (fl & 1) ? ((long)cn*ldc + gm) : ((long)gm*ldc + cn);
          if (fl & 2) v += prd(Cp, idx, lo);
          short h, l; split1(v, h, l);
          Cp[idx] = h; Cp[idx + lo] = l;
        }
      }
    }
  }
}

// =======================================================================
// scores GEMM (A via LDS, B direct) + fused wave-parallel row softmax.
// =======================================================================
template<int NN, bool A16, int DB>
__global__ __launch_bounds__(256) void gemm_sm(
    const short* __restrict__ Ag, long loA, const short* __restrict__ Bg, long loB,
    int K, long lda, long ldb,
    int nz1, long sA, long sB, long sA2, long sB2,
    float* __restrict__ Sg, long sS, long sS2, int ldS,
    float mult, const int* __restrict__ lengths, int b0,
    const float* __restrict__ mulP, long sMul)
{
  __shared__ short As_h[128*40], As_l[128*40];
  const int tid = threadIdx.x;
  const int z1 = blockIdx.z % nz1, z2 = blockIdx.z / nz1;
  const int m0 = blockIdx.y*128;
  const short* A = Ag + z1*sA + z2*sA2;
  const short* B = Bg + z1*sB + z2*sB2;
  float* S = Sg + z1*sS + z2*sS2;

  const int srow = tid >> 1, sc0 = (tid & 1)*16;
  const int lane = tid & 63, wv = tid >> 6;
  const int wm = (wv >> 1)*64, wn = (wv & 1)*64;
  const int fr = lane & 15, kq = (lane >> 4)*8;
  const int cr = (lane >> 4)*4, cc = lane & 15;

  for (int nh = 0; nh < NN; nh += 128){
    RegsP rA;
    ld_pair<A16>(A, loA, lda, 0, K, m0+srow, true, sc0, rA);
    int4 bhv[2][4], blv[2][4];
    ldB_frag<DB>(B, loB, ldb, 0, K, NN, nh+wn, fr, kq, bhv[0], blv[0]);
    f32x4 acc[4][4] = {};
    int p = 0;
    for (int kb = 0; kb < K; kb += 32, p ^= 1){
      wr_pair(rA, As_h, As_l, srow, sc0);
      __syncthreads();
      const int kn = kb + 32;
      if (kn < K){
        ld_pair<A16>(A, loA, lda, kn, K, m0+srow, true, sc0, rA);
        ldB_frag<DB>(B, loB, ldb, kn, K, NN, nh+wn, fr, kq, bhv[p^1], blv[p^1]);
      }
      bf16x8v ah[4], al[4];
      #pragma unroll
      for (int i=0;i<4;++i){
        ah[i] = *reinterpret_cast<const bf16x8v*>(&As_h[(wm + i*16 + fr)*40 + kq]);
        al[i] = *reinterpret_cast<const bf16x8v*>(&As_l[(wm + i*16 + fr)*40 + kq]);
      }
      #pragma unroll
      for (int i=0;i<4;++i)
        #pragma unroll
        for (int j=0;j<4;++j){
          const bf16x8v bh = __builtin_bit_cast(bf16x8v, bhv[p][j]);
          const bf16x8v bl = __builtin_bit_cast(bf16x8v, blv[p][j]);
          acc[i][j] = __builtin_amdgcn_mfma_f32_16x16x32_bf16(ah[i], bh, acc[i][j], 0,0,0);
          acc[i][j] = __builtin_amdgcn_mfma_f32_16x16x32_bf16(ah[i], bl, acc[i][j], 0,0,0);
          acc[i][j] = __builtin_amdgcn_mfma_f32_16x16x32_bf16(al[i], bh, acc[i][j], 0,0,0);
        }
      __syncthreads();
    }
    #pragma unroll
    for (int i=0;i<4;++i)
      #pragma unroll
      for (int j=0;j<4;++j)
        #pragma unroll
        for (int rr=0;rr<4;++rr){
          const int gm = m0 + wm + i*16 + cr + rr;
          const int gn = nh + wn + j*16 + cc;
          S[(long)gm*ldS + gn] = acc[i][j][rr] * mult;
        }
  }
  __syncthreads();   // S fully written, block-visible

  // ---- wave-parallel row softmax: wave wv owns rows m0+wv*32 .. +31 ----
  constexpr int CH = NN / 64;               // cols per lane: 2 or 4
  const int cbase = lane*CH;
  int lim = NN;
  if (lengths){ const int L = lengths[b0 + z1]; lim = (L < NN) ? L : NN; }

  float v[CH], vn[CH], mcur[CH], mnxt[CH];
  {
    float* row0 = S + (long)(m0 + wv*32)*ldS + cbase;
    #pragma unroll
    for (int e=0;e<CH;++e) v[e] = row0[e];
    if (mulP){
      const float* mr = mulP + z1*sMul + (long)(m0 + wv*32)*ldS + cbase;
      #pragma unroll
      for (int e=0;e<CH;++e) mcur[e] = mr[e];
    }
  }
  for (int i = 0; i < 32; ++i){
    if (i < 31){
      float* rn = S + (long)(m0 + wv*32 + i + 1)*ldS + cbase;
      #pragma unroll
      for (int e=0;e<CH;++e) vn[e] = rn[e];
      if (mulP){
        const float* mr = mulP + z1*sMul + (long)(m0 + wv*32 + i + 1)*ldS + cbase;
        #pragma unroll
        for (int e=0;e<CH;++e) mnxt[e] = mr[e];
      }
    }
    float mx = -3.0e38f;
    #pragma unroll
    for (int e=0;e<CH;++e) if (cbase+e < lim) mx = fmaxf(mx, v[e]);
    #pragma unroll
    for (int o=32;o>0;o>>=1) mx = fmaxf(mx, __shfl_xor(mx, o, 64));
    float sm = 0.f;
    #pragma unroll
    for (int e=0;e<CH;++e){
      v[e] = (cbase+e < lim) ? __expf(v[e] - mx) : 0.f;
      sm += v[e];
    }
    #pragma unroll
    for (int o=32;o>0;o>>=1) sm += __shfl_xor(sm, o, 64);
    const float inv = 1.f / sm;
    float* row = S + (long)(m0 + wv*32 + i)*ldS + cbase;
    if (mulP){
      #pragma unroll
      for (int e=0;e<CH;++e) row[e] = v[e]*inv*mcur[e];
    } else {
      #pragma unroll
      for (int e=0;e<CH;++e) row[e] = v[e]*inv;
    }
    #pragma unroll
    for (int e=0;e<CH;++e){ v[e] = vn[e]; mcur[e] = mnxt[e]; }
  }
}

// ---------------- hg chunk init (pair out) ----------------
__global__ void build_hg(const void* __restrict__ src, const short* __restrict__ Ru, long loW,
                         short* __restrict__ hg, long loH, const int* __restrict__ flag, int b0){
  const int t = blockIdx.x, bl = blockIdx.y, se = threadIdx.x;  // block 128
  const int f32 = *flag;
  const float s = rdIn(src, ((long)t*B_ + (b0+bl))*(2*SE_) + se, f32);
  const long o = ((long)bl*SE_ + se)*1024 + t*4;
  #pragma unroll
  for (int j=0;j<4;++j){
    const float v = fmaxf(s * prd(Ru, se*4+j, loW), 0.f);
    short h, l; split1(v, h, l);
    hg[o+j] = h; hg[o+j+loH] = l;
  }
}

// ---------------- xx chunk build (pair in/out) ----------------
__global__ void build_xx(const short* __restrict__ hg, long loH,
                         const short* __restrict__ times, long loW,
                         short* __restrict__ xx, long loX, int b0, int G){
  const int blk = blockIdx.x;          // t*G + bl
  const int t = blk / G, bl = blk % G, b = b0 + bl;
  const int tid = threadIdx.x;
  const float tm = prd(times, (long)t*B_ + b, loW);
  for (int c = tid; c < D_MODEL_; c += 256){
    float v;
    if (c < SE_*4){
      v = prd(hg, ((long)bl*SE_ + (c>>2))*1024 + t*4 + (c&3), loH);
    } else {
      const int p = c - SE_*4;
      const int i = p & 7;
      const float ts = exp2f(8.0f * (float)i / 7.0f);
      const float st = tm / ts;
      v = (p < 8) ? sinf(st) : cosf(st);
    }
    short h, l; split1(v, h, l);
    const long o = ((long)t*B_ + b)*D_MODEL_ + c;
    xx[o] = h; xx[o+loX] = l;
  }
}

// ---------------- LN body (row = 528, pairs) ----------------
__device__ __forceinline__ void ln_body_p(short* px, long loX, const short* pr, long loR,
                                          const short* g, const short* bb, long loW, int tid){
  const float x0 = prd(px,tid,loX)     + prd(pr,tid,loR);
  const float x1 = prd(px,tid+256,loX) + prd(pr,tid+256,loR);
  const float x2 = (tid < 16) ? (prd(px,tid+512,loX) + prd(pr,tid+512,loR)) : 0.f;
  __shared__ float rs[256], rq[256];
  rs[tid] = x0 + x1 + x2;
  rq[tid] = x0*x0 + x1*x1 + x2*x2;
  __syncthreads();
  for (int h = 128; h > 0; h >>= 1){
    if (tid < h){ rs[tid] += rs[tid+h]; rq[tid] += rq[tid+h]; }
    __syncthreads();
  }
  const float mean = rs[0] * (1.0f/528.0f);
  const float var  = rq[0] * (1.0f/528.0f) - mean*mean;
  const float inv = rsqrtf(var + 1e-5f);
  short h, l;
  split1((x0-mean)*inv*prd(g,tid,loW) + prd(bb,tid,loW), h, l);
  px[tid] = h; px[tid+loX] = l;
  split1((x1-mean)*inv*prd(g,tid+256,loW) + prd(bb,tid+256,loW), h, l);
  px[tid+256] = h; px[tid+256+loX] = l;
  if (tid < 16){
    split1((x2-mean)*inv*prd(g,tid+512,loW) + prd(bb,tid+512,loW), h, l);
    px[tid+512] = h; px[tid+512+loX] = l;
  }
}

__global__ __launch_bounds__(256) void ln_res_attn(short* __restrict__ xx, long loX,
    const short* __restrict__ res, long loR,
    const short* __restrict__ g, const short* __restrict__ bb, long loW, int b0){
  const int z = blockIdx.x >> 8, t = blockIdx.x & 255;
  short* px = xx + ((long)t*B_ + b0 + z)*D_MODEL_;
  const short* pr = res + (long)blockIdx.x*D_MODEL_;
  ln_body_p(px, loX, pr, loR, g, bb, loW, threadIdx.x);
}

__global__ __launch_bounds__(256) void ln_res_rows(short* __restrict__ xx, long loX,
    const short* __restrict__ res, long loR,
    const short* __restrict__ g, const short* __restrict__ bb, long loW, int r0){
  short* px = xx + ((long)r0 + blockIdx.x)*D_MODEL_;
  const short* pr = res + (long)blockIdx.x*D_MODEL_;
  ln_body_p(px, loX, pr, loR, g, bb, loW, threadIdx.x);
}

// ---------------- masked mean pool (pair in/out) ----------------
__global__ void pool_k(const short* __restrict__ xx, long loX, const int* __restrict__ len,
                       short* __restrict__ pooled, long loP){
  const int b = blockIdx.y;
  const int c = blockIdx.x*256 + threadIdx.x;
  if (c >= D_MODEL_) return;
  const int L = len[b];
  float s = 0.f;
  for (int t = 0; t < L; ++t) s += prd(xx, ((long)t*B_ + b)*D_MODEL_ + c, loX);
  short h, l; split1(s / (float)(L + 1), h, l);
  pooled[(long)b*D_FINAL_ + c] = h;
  pooled[(long)b*D_FINAL_ + c + loP] = l;
}

// ---------------- logits (pair in, out dtype per flag) ----------------
__global__ void logits_k(const short* __restrict__ hid, long loH,
                         const short* __restrict__ W2, const short* __restrict__ b2, long loW,
                         void* __restrict__ out, const int* __restrict__ flag){
  const int z = blockIdx.x;            // b*2 + c
  const int b = z >> 1, c = z & 1;
  const int lane = threadIdx.x;        // 64
  float s = 0.f;
  for (int k = lane; k < D_FINAL_; k += 64)
    s += prd(hid, (long)b*D_FINAL_ + k, loH) * prd(W2, (long)c*D_FINAL_ + k, loW);
  #pragma unroll
  for (int o = 32; o > 0; o >>= 1) s += __shfl_down(s, o, 64);
  if (lane == 0){
    const float r = s + prd(b2, c, loW);
    if (*flag) ((float*)out)[z] = r;
    else       ((bf16*)out)[z] = __float2bfloat16(r);
  }
}

// =======================================================================
// Arena identical to round 8 (peak ~155 MiB, proven cap 167.3 MiB).
// =======================================================================
extern "C" void kernel_launch(void* const* d_in, const int* in_sizes, int n_in,
                              void* d_out, int out_size, void* d_ws, size_t ws_size,
                              hipStream_t stream) {
  const int* lengths = (const int*)d_in[2];
  char* ws = (char*)d_ws;
  const size_t KB = 1024;

  short* wtsH = (short*)ws;
  int* flag = (int*)(ws + 47500*KB);
  short* xxH = (short*)(ws + 48000*KB);
  const long loXX = 17301504;
  char* SC = ws + 115600*KB;

  short* hgA = (short*)(SC + 0*KB);      const long loHG = 2097152;
  short* hgB = (short*)(SC + 8192*KB);
  short* qkc = (short*)(SC + 16384*KB);  const long loQK1 = 4194304;
  short* VtS = (short*)(SC + 32768*KB);  const long loVT1 = 2097152;
  float* S0c = (float*)(SC + 40960*KB);
  float* S1c = (float*)(SC + 41984*KB);
  short* qkb = (short*)(SC + 0*KB);      const long loQK2 = 4325376;
  short* o_c = (short*)(SC + 0*KB);      const long loOC  = 2162688;
  short* pjb = (short*)(SC + 8448*KB);   const long loPJ  = 2162688;
  short* vtb = (short*)(SC + 16896*KB);  const long loVT2 = 2162688;
  float* att = (float*)(SC + 25344*KB);
  short* ff1 = (short*)(SC + 0*KB);      const long loFF  = 4194304;
  short* pj2 = (short*)(SC + 16896*KB);  const long loPJ2 = 4325376;
  short* pooled = (short*)(SC + 0*KB);   const long loPO  = 133120;
  short* hid    = (short*)(SC + 1024*KB);

  CvtTab tb; long cur = 0; int nb = 0; int e = 0;
  auto add = [&](int idx, long so, long n)->long{
    tb.src[e] = d_in[idx]; tb.srcOff[e] = so; tb.dstOff[e] = cur;
    tb.n[e] = (int)n; tb.bstart[e] = nb;
    nb += (int)((n + 255)/256); cur += n; e++;
    return cur - n;
  };
  const long oT  = add(1,0,32768);
  const long oSt = add(3,0,8192);
  const long oRu = add(4,0,512);
  const long oSW = add(5,0,32768);
  const long oSb = add(6,0,512);
  long oQKSV[2], oBQ[2];
  for (int l = 0; l < 2; ++l){
    oQKSV[l] = add(7, (long)l*1048576, 1048576);
    add(8,  (long)l*1048576, 1048576);
    add(13, (long)l*1048576, 1048576);
    add(9,  (long)l*1048576, 1048576);
  }
  for (int l = 0; l < 2; ++l){
    oBQ[l] = add(10, (long)l*1024, 1024);
    add(11, (long)l*1024, 1024);
    add(14, (long)l*1024, 1024);
    add(12, (long)l*1024, 1024);
  }
  const long oWqkv = add(15,0,1672704);
  const long obqkv = add(16,0,3168);
  const long oWo = add(17,0,557568);
  const long obo = add(18,0,1056);
  const long oW1 = add(19,0,135168);
  const long ob1 = add(20,0,256);
  const long oW2 = add(21,0,135168);
  const long ob2 = add(22,0,1056);
  const long og1 = add(23,0,1056);
  const long obb1 = add(24,0,1056);
  const long og2 = add(25,0,1056);
  const long obb2 = add(26,0,1056);
  const long oM1 = add(27,0,1081600);
  const long oM1b = add(28,0,1040);
  const long oM2 = add(29,0,2080);
  const long oM2b = add(30,0,2);
  tb.cnt = e;
  const long loW = (cur + 7) & ~7L;

  detect_k<<<1,256,0,stream>>>(d_in[0], flag);
  cvt_all<<<nb,256,0,stream>>>(tb, wtsH, loW, flag);

  const Route RZ{nullptr,0,0,0,0,0,0};

  // ================= stage 1: propagation (16-batch chunks) =================
  const int G1 = 16;
  for (int b0 = 0; b0 < B_; b0 += G1){
    build_hg<<<dim3(T_, G1), 128, 0, stream>>>(d_in[0], wtsH+oRu, loW, hgA, loHG, flag, b0);
    short* curb = hgA; short* nxtb = hgB;
    for (int l = 0; l < 2; ++l){
      float* S = (l == 0) ? S0c : S1c;
      {
        Route q{qkc, 2048, loQK1, 0, 0, 2048, 0};
        Route s{nxtb, 1024, loHG, 0, 0, 3072, 0};
        Route v{VtS, 2048, loVT1, 0, 0, 4096, 1};
        gemm_s<false,true,16><<<dim3(32,16,1),256,0,stream>>>(
            curb, loHG, wtsH+oQKSV[l], loW, wtsH+oBQ[l], loW,
            2048, 4096, 1024, 1024, 1024,
            1, 0,0,0,0, 0, 3, q, s, v, 1.f);
      }
      gemm_sm<128,true,16><<<dim3(1,1,G1),256,0,stream>>>(
          qkc, loQK1, qkc+1024, loQK1,
          1024, 2048, 2048,
          G1, 262144, 262144, 0, 0,
          S, 16384, 0, 128,
          0.03125f, nullptr, 0,
          (l == 1) ? S0c : nullptr, 16384);
      {
        Route c{nxtb, 1024, loHG, 131072, 0, 1024, 2};
        gemm_s<true,true,16><<<dim3(8,1,G1),256,0,stream>>>(
            S, 0, VtS, loVT1, nullptr, 0,
            128, 1024, 128, 128, 2048,
            G1, 16384, 128, 0, 0, 0, 1, c, RZ, RZ, 1.f);
      }
      short* t_ = curb; curb = nxtb; nxtb = t_;
    }
    build_xx<<<T_*G1,256,0,stream>>>(curb, loHG, wtsH+oT, loW, xxH, loXX, b0, G1);
  }

  // ================= stage 2: transformer (16-batch chunks) =================
  const float iscl = 1.0f / sqrtf((float)HD_);
  const int G2 = 16;
  for (int l = 0; l < 2; ++l){
    const long wqkv = oWqkv + (long)l*836352;
    const long bqkv = obqkv + (long)l*1584;
    for (int b0 = 0; b0 < B_; b0 += G2){
      {
        Route qk{qkb, 1056, loQK2, 270336, 0, 1056, 0};
        Route v{vtb, 256, loVT2, 135168, 0, 1584, 1};
        gemm_s<false,true,16><<<dim3(13,2,G2),256,0,stream>>>(
            xxH + (long)b0*D_MODEL_, loXX, wtsH+wqkv, loW, wtsH+bqkv, loW,
            256, 1584, 528, (long)B_*D_MODEL_, 528,
            G2, 528, 0, 0, 0, 0, 2, qk, v, RZ, 1.f);
      }
      gemm_sm<256,false,8><<<dim3(1,2,G2*NH_),256,0,stream>>>(
          qkb, loQK2, qkb+528, loQK2,
          132, 1056, 1056,
          G2, 270336, 270336, 132, 132,
          att, 262144, 65536, 256,
          iscl, lengths, b0, nullptr, 0);
      {
        Route c{o_c, 528, loOC, 135168, 132, HD_, 0};
        gemm_s<true,true,16><<<dim3(2,2,G2*NH_),256,0,stream>>>(
            att, 0, vtb, loVT2, nullptr, 0,
            256, HD_, 256, 256, 256,
            G2, 262144, 135168, 65536, 33792, 0, 1, c, RZ, RZ, 1.f);
      }
      {
        Route c{pjb, 528, loPJ, 135168, 0, 528, 0};
        gemm_s<false,true,16><<<dim3(5,2,G2),256,0,stream>>>(
            o_c, loOC, wtsH+oWo+(long)l*278784, loW, wtsH+obo+(long)l*528, loW,
            256, 528, 528, 528, 528,
            G2, 135168, 0, 0, 0, 0, 1, c, RZ, RZ, 1.f);
      }
      ln_res_attn<<<G2*256,256,0,stream>>>(xxH, loXX, pjb, loPJ,
          wtsH+og1+(long)l*528, wtsH+obb1+(long)l*528, loW, b0);
    }
    {
      Route c{ff1, 128, loFF, 0, 0, 128, 0};
      gemm_s<false,true,16><<<dim3(1,256,1),256,0,stream>>>(
          xxH, loXX, wtsH+oW1+(long)l*67584, loW, wtsH+ob1+(long)l*128, loW,
          32768, 128, 528, 528, 528,
          1, 0,0,0,0, 1, 1, c, RZ, RZ, 1.f);
    }
    for (int r0 = 0; r0 < 32768; r0 += 8192){
      Route c{pj2, 528, loPJ2, 0, 0, 528, 0};
      gemm_s<false,true,16><<<dim3(5,64,1),256,0,stream>>>(
          ff1 + (long)r0*128, loFF, wtsH+oW2+(long)l*67584, loW, wtsH+ob2+(long)l*528, loW,
          8192, 528, 128, 128, 128,
          1, 0,0,0,0, 0, 1, c, RZ, RZ, 1.f);
      ln_res_rows<<<8192,256,0,stream>>>(xxH, loXX, pj2, loPJ2,
          wtsH+og2+(long)l*528, wtsH+obb2+(long)l*528, loW, r0);
    }
  }

  // ================= stage 3: pool + MLP head =================
  pool_k<<<dim3(3,B_),256,0,stream>>>(xxH, loXX, lengths, pooled, loPO);
  {
    Route c{pooled + D_MODEL_, 1040, loPO, 0, 0, 512, 0};
    gemm_s<false,true,16><<<dim3(4,1,1),256,0,stream>>>(
        wtsH+oSt, loW, wtsH+oSW, loW, wtsH+oSb, loW,
        128, 512, 64, 64, 64,
        1, 0,0,0,0, 0, 1, c, RZ, RZ, 1.f);
  }
  {
    Route c{hid, 1040, loPO, 0, 0, 1040, 0};
    gemm_s<false,true,16><<<dim3(9,1,1),256,0,stream>>>(
        pooled, loPO, wtsH+oM1, loW, wtsH+oM1b, loW,
        128, 1040, 1040, 1040, 1040,
        1, 0,0,0,0, 1, 1, c, RZ, RZ, 1.f);
  }
  logits_k<<<B_*2,64,0,stream>>>(hid, loPO, wtsH+oM2, wtsH+oM2b, loW, d_out, flag);
}

// Round 10
// 8289.096 us; speedup vs baseline: 1.6580x; 1.6580x over previous
//
#include <hip/hip_runtime.h>
#include <hip/hip_bf16.h>
#include <math.h>

#define SE_    128
#define T_     256
#define B_     128
#define NH_    4
#define HD_    132
#define D_MODEL_ 528
#define D_FINAL_ 1040
#define D_FF_  128

typedef __hip_bfloat16 bf16;
typedef __attribute__((ext_vector_type(8))) short bf16x8v;
typedef __attribute__((ext_vector_type(4))) float f32x4;

__device__ __forceinline__ float bfb(unsigned short u){
  union { float f; unsigned int i; } c; c.i = ((unsigned int)u) << 16; return c.f;
}
__device__ __forceinline__ unsigned short bfr(float x){
  unsigned u = __builtin_bit_cast(unsigned, x);
  unsigned r = (u + 0x7FFFu + ((u >> 16) & 1u)) >> 16;
  return (unsigned short)r;
}
__device__ __forceinline__ void split1(float x, short& h, short& l){
  const unsigned short hu = bfr(x);
  const unsigned short lu = bfr(x - bfb(hu));
  h = (short)hu; l = (short)lu;
}
__device__ __forceinline__ float prd(const short* p, long i, long lo){
  return bfb((unsigned short)p[i]) + bfb((unsigned short)p[i+lo]);
}
__device__ __forceinline__ float rdIn(const void* p, long i, int f32){
  return f32 ? ((const float*)p)[i] : __bfloat162float(((const bf16*)p)[i]);
}

// ---------------- dtype detect: 1 = f32 inputs, 0 = bf16 ----------------
__global__ void detect_k(const void* __restrict__ src, int* __restrict__ flag){
  const unsigned int* p = (const unsigned int*)src;
  int bad = 0;
  for (int i = threadIdx.x; i < 4096; i += 256){
    const unsigned int lo = p[i] & 0xFFFFu;
    const unsigned int e = (lo >> 7) & 0xFFu;
    if (e >= 0xC0u) bad++;
  }
  __shared__ int red[256];
  red[threadIdx.x] = bad; __syncthreads();
  for (int h = 128; h > 0; h >>= 1){
    if (threadIdx.x < h) red[threadIdx.x] += red[threadIdx.x+h];
    __syncthreads();
  }
  if (threadIdx.x == 0) *flag = (red[0] > 64) ? 1 : 0;
}

// ---------------- mega conversion: all weights -> hi/lo bf16 planes ----------------
#define MAXE 40
struct CvtTab {
  const void* src[MAXE];
  long srcOff[MAXE];
  long dstOff[MAXE];
  int n[MAXE];
  int bstart[MAXE];
  int cnt;
};
__global__ void cvt_all(CvtTab tb, short* __restrict__ wts, long loW, const int* __restrict__ flag){
  const int b = blockIdx.x;
  int e = 0;
  for (int i = 1; i < tb.cnt; ++i) if (tb.bstart[i] <= b) e = i;
  const long i = (long)(b - tb.bstart[e])*256 + threadIdx.x;
  if (i >= tb.n[e]) return;
  const float v = rdIn(tb.src[e], tb.srcOff[e] + i, *flag);
  short h, l; split1(v, h, l);
  wts[tb.dstOff[e] + i] = h;
  wts[tb.dstOff[e] + i + loW] = l;
}

// ---------------- A K-tile register loads (prefetchable) ----------------
struct RegsP { int4 v[4]; };   // [0..1]=hi 16 shorts, [2..3]=lo

template<bool A16>
__device__ __forceinline__ void ld_pair(const short* __restrict__ P, long lo, long ld,
                                        int kb, int K, int g, bool valid, int sc0, RegsP& r){
  short* a = (short*)r.v;
  const int k0 = kb + sc0;
  const short* ph = P + (long)g*ld + k0;
  if (valid && (k0 + 16 <= K)){
    if (A16){
      r.v[0] = *(const int4*)(ph);
      r.v[1] = *(const int4*)(ph + 8);
      r.v[2] = *(const int4*)(ph + lo);
      r.v[3] = *(const int4*)(ph + lo + 8);
    } else {
      #pragma unroll
      for (int q=0;q<4;++q){
        *(int2*)(a + q*4)      = *(const int2*)(ph + q*4);
        *(int2*)(a + 16 + q*4) = *(const int2*)(ph + lo + q*4);
      }
    }
  } else {
    #pragma unroll
    for (int e2=0;e2<16;++e2){
      const bool ok = valid && (k0 + e2 < K);
      a[e2]    = ok ? ph[e2] : (short)0;
      a[16+e2] = ok ? ph[lo + e2] : (short)0;
    }
  }
}

__device__ __forceinline__ void ld_f32(const float* __restrict__ P, long ld, int kb, int K,
                                       int g, bool valid, int sc0, float* f){
  const int k0 = kb + sc0;
  const float* p = P + (long)g*ld + k0;
  if (valid && (k0 + 16 <= K)){
    #pragma unroll
    for (int q=0;q<4;++q) *(float4*)(f+q*4) = *(const float4*)(p + q*4);
  } else {
    #pragma unroll
    for (int e2=0;e2<16;++e2) f[e2] = (valid && (k0+e2) < K) ? p[e2] : 0.f;
  }
}

__device__ __forceinline__ void wr_pair(const RegsP& r, short* Lh, short* Ll, int srow, int sc0){
  *(int4*)(&Lh[srow*40 + sc0])     = r.v[0];
  *(int4*)(&Lh[srow*40 + sc0 + 8]) = r.v[1];
  *(int4*)(&Ll[srow*40 + sc0])     = r.v[2];
  *(int4*)(&Ll[srow*40 + sc0 + 8]) = r.v[3];
}
__device__ __forceinline__ void wr_split(const float* f, short* Lh, short* Ll, int srow, int sc0){
  short h[16], l[16];
  #pragma unroll
  for (int e2=0;e2<16;++e2) split1(f[e2], h[e2], l[e2]);
  *(int4*)(&Lh[srow*40+sc0])   = *(const int4*)(h);
  *(int4*)(&Lh[srow*40+sc0+8]) = *(const int4*)(h+8);
  *(int4*)(&Ll[srow*40+sc0])   = *(const int4*)(l);
  *(int4*)(&Ll[srow*40+sc0+8]) = *(const int4*)(l+8);
}

// ---------------- direct-to-register B MFMA fragments (STATIC indexing) ----------------
struct BFrag { int4 h[4]; int4 l[4]; };

template<int DB>
__device__ __forceinline__ void ldB_frag(const short* __restrict__ Bf, long lo, long ldb,
                                         int kb, int K, int N, int nbase, int fr, int kq,
                                         BFrag& r){
  const int k0 = kb + kq;
  #pragma unroll
  for (int j=0;j<4;++j){
    int gn = nbase + j*16 + fr;
    if (gn >= N) gn = N-1;                 // clamped rows feed discarded C cols
    const short* p = Bf + (long)gn*ldb + k0;
    if (k0 + 8 <= K){
      if (DB == 16){
        r.h[j] = *(const int4*)(p);
        r.l[j] = *(const int4*)(p + lo);
      } else {
        int2* h2 = (int2*)&r.h[j]; int2* l2 = (int2*)&r.l[j];
        h2[0] = *(const int2*)(p);      h2[1] = *(const int2*)(p + 4);
        l2[0] = *(const int2*)(p + lo); l2[1] = *(const int2*)(p + lo + 4);
      }
    } else {
      short* hs = (short*)&r.h[j]; short* ls = (short*)&r.l[j];
      #pragma unroll
      for (int e=0;e<8;++e){
        const bool ok = (k0 + e) < K;
        hs[e] = ok ? p[e] : (short)0;
        ls[e] = ok ? p[lo + e] : (short)0;
      }
    }
  }
}

// =======================================================================
// bf16x3 emulated-f32 NT GEMM: A via LDS, B direct-to-register (static
// double buffer, no spills), pair-plane operands, routed pair epilogue.
// =======================================================================
struct Route { short* C; long ldc; long lo; long sC; long sC2; int nEnd; int fl; }; // fl: 1=trans 2=acc

template<bool SPLITA, bool A16, int DB>
__global__ __launch_bounds__(256, 2) void gemm_s(
    const void* __restrict__ Ag, long loA,
    const short* __restrict__ Bg, long loB,
    const short* __restrict__ bias, long loBias,
    int M, int N, int K, long lda, long ldb,
    int nz1, long sA, long sB, long sA2, long sB2,
    int relu, int nroute, Route r0, Route r1, Route r2, float mult)
{
  __shared__ short As_h[128*40], As_l[128*40];
  const int tid = threadIdx.x;
  const int z1 = blockIdx.z % nz1, z2 = blockIdx.z / nz1;
  const int m0 = blockIdx.y*128, n0 = blockIdx.x*128;
  const void* A;
  if (SPLITA) A = (const void*)((const float*)Ag + z1*sA + z2*sA2);
  else        A = (const void*)((const short*)Ag + z1*sA + z2*sA2);
  const short* B = Bg + z1*sB + z2*sB2;
  short* Cb0 = r0.C + z1*r0.sC + z2*r0.sC2;
  short* Cb1 = (nroute > 1) ? (r1.C + z1*r1.sC + z2*r1.sC2) : nullptr;
  short* Cb2 = (nroute > 2) ? (r2.C + z1*r2.sC + z2*r2.sC2) : nullptr;

  const int srow = tid >> 1, sc0 = (tid & 1)*16;
  const int lane = tid & 63, wv = tid >> 6;
  const int wm = (wv >> 1)*64, wn = (wv & 1)*64;
  const int fr = lane & 15, kq = (lane >> 4)*8;

  const int gm_s = m0 + srow; const bool mval = gm_s < M;

  RegsP rA; float fA[16];
  if (SPLITA) ld_f32((const float*)A, lda, 0, K, gm_s, mval, sc0, fA);
  else        ld_pair<A16>((const short*)A, loA, lda, 0, K, gm_s, mval, sc0, rA);
  BFrag bc, bn;
  ldB_frag<DB>(B, loB, ldb, 0, K, N, n0+wn, fr, kq, bc);

  f32x4 acc[4][4] = {};
  for (int kb = 0; kb < K; kb += 32){
    if (SPLITA) wr_split(fA, As_h, As_l, srow, sc0);
    else        wr_pair(rA, As_h, As_l, srow, sc0);
    __syncthreads();
    const int kn = kb + 32;
    if (kn < K){
      if (SPLITA) ld_f32((const float*)A, lda, kn, K, gm_s, mval, sc0, fA);
      else        ld_pair<A16>((const short*)A, loA, lda, kn, K, gm_s, mval, sc0, rA);
      ldB_frag<DB>(B, loB, ldb, kn, K, N, n0+wn, fr, kq, bn);
    }
    bf16x8v ah[4], al[4];
    #pragma unroll
    for (int i=0;i<4;++i){
      ah[i] = *reinterpret_cast<const bf16x8v*>(&As_h[(wm + i*16 + fr)*40 + kq]);
      al[i] = *reinterpret_cast<const bf16x8v*>(&As_l[(wm + i*16 + fr)*40 + kq]);
    }
    #pragma unroll
    for (int j=0;j<4;++j){
      const bf16x8v bh = __builtin_bit_cast(bf16x8v, bc.h[j]);
      const bf16x8v bl = __builtin_bit_cast(bf16x8v, bc.l[j]);
      #pragma unroll
      for (int i=0;i<4;++i){
        acc[i][j] = __builtin_amdgcn_mfma_f32_16x16x32_bf16(ah[i], bh, acc[i][j], 0,0,0);
        acc[i][j] = __builtin_amdgcn_mfma_f32_16x16x32_bf16(ah[i], bl, acc[i][j], 0,0,0);
        acc[i][j] = __builtin_amdgcn_mfma_f32_16x16x32_bf16(al[i], bh, acc[i][j], 0,0,0);
      }
    }
    __syncthreads();
    if (kn < K) bc = bn;
  }

  const int cr = (lane >> 4)*4, cc = lane & 15;
  #pragma unroll
  for (int i=0;i<4;++i){
    #pragma unroll
    for (int j=0;j<4;++j){
      #pragma unroll
      for (int rr=0;rr<4;++rr){
        const int gm = m0 + wm + i*16 + cr + rr;
        const int gn = n0 + wn + j*16 + cc;
        if (gm < M && gn < N){
          float v = acc[i][j][rr] * mult;
          if (bias) v += prd(bias, gn, loBias);
          if (relu) v = fmaxf(v, 0.f);
          short* Cp; long ldc, lo; int fl, cn;
          if (nroute > 1 && gn >= r0.nEnd){
            if (nroute > 2 && gn >= r1.nEnd){ Cp=Cb2; ldc=r2.ldc; lo=r2.lo; fl=r2.fl; cn=gn-r1.nEnd; }
            else                            { Cp=Cb1; ldc=r1.ldc; lo=r1.lo; fl=r1.fl; cn=gn-r0.nEnd; }
          } else                            { Cp=Cb0; ldc=r0.ldc; lo=r0.lo; fl=r0.fl; cn=gn; }
          const long idx = (fl & 1) ? ((long)cn*ldc + gm) : ((long)gm*ldc + cn);
          if (fl & 2) v += prd(Cp, idx, lo);
          short h, l; split1(v, h, l);
          Cp[idx] = h; Cp[idx + lo] = l;
        }
      }
    }
  }
}

// =======================================================================
// scores GEMM (A via LDS, B direct static-dbuf) + fused wave softmax.
// =======================================================================
template<int NN, bool A16, int DB>
__global__ __launch_bounds__(256, 2) void gemm_sm(
    const short* __restrict__ Ag, long loA, const short* __restrict__ Bg, long loB,
    int K, long lda, long ldb,
    int nz1, long sA, long sB, long sA2, long sB2,
    float* __restrict__ Sg, long sS, long sS2, int ldS,
    float mult, const int* __restrict__ lengths, int b0,
    const float* __restrict__ mulP, long sMul)
{
  __shared__ short As_h[128*40], As_l[128*40];
  const int tid = threadIdx.x;
  const int z1 = blockIdx.z % nz1, z2 = blockIdx.z / nz1;
  const int m0 = blockIdx.y*128;
  const short* A = Ag + z1*sA + z2*sA2;
  const short* B = Bg + z1*sB + z2*sB2;
  float* S = Sg + z1*sS + z2*sS2;

  const int srow = tid >> 1, sc0 = (tid & 1)*16;
  const int lane = tid & 63, wv = tid >> 6;
  const int wm = (wv >> 1)*64, wn = (wv & 1)*64;
  const int fr = lane & 15, kq = (lane >> 4)*8;
  const int cr = (lane >> 4)*4, cc = lane & 15;

  for (int nh = 0; nh < NN; nh += 128){
    RegsP rA;
    ld_pair<A16>(A, loA, lda, 0, K, m0+srow, true, sc0, rA);
    BFrag bc, bn;
    ldB_frag<DB>(B, loB, ldb, 0, K, NN, nh+wn, fr, kq, bc);
    f32x4 acc[4][4] = {};
    for (int kb = 0; kb < K; kb += 32){
      wr_pair(rA, As_h, As_l, srow, sc0);
      __syncthreads();
      const int kn = kb + 32;
      if (kn < K){
        ld_pair<A16>(A, loA, lda, kn, K, m0+srow, true, sc0, rA);
        ldB_frag<DB>(B, loB, ldb, kn, K, NN, nh+wn, fr, kq, bn);
      }
      bf16x8v ah[4], al[4];
      #pragma unroll
      for (int i=0;i<4;++i){
        ah[i] = *reinterpret_cast<const bf16x8v*>(&As_h[(wm + i*16 + fr)*40 + kq]);
        al[i] = *reinterpret_cast<const bf16x8v*>(&As_l[(wm + i*16 + fr)*40 + kq]);
      }
      #pragma unroll
      for (int j=0;j<4;++j){
        const bf16x8v bh = __builtin_bit_cast(bf16x8v, bc.h[j]);
        const bf16x8v bl = __builtin_bit_cast(bf16x8v, bc.l[j]);
        #pragma unroll
        for (int i=0;i<4;++i){
          acc[i][j] = __builtin_amdgcn_mfma_f32_16x16x32_bf16(ah[i], bh, acc[i][j], 0,0,0);
          acc[i][j] = __builtin_amdgcn_mfma_f32_16x16x32_bf16(ah[i], bl, acc[i][j], 0,0,0);
          acc[i][j] = __builtin_amdgcn_mfma_f32_16x16x32_bf16(al[i], bh, acc[i][j], 0,0,0);
        }
      }
      __syncthreads();
      if (kn < K) bc = bn;
    }
    #pragma unroll
    for (int i=0;i<4;++i)
      #pragma unroll
      for (int j=0;j<4;++j)
        #pragma unroll
        for (int rr=0;rr<4;++rr){
          const int gm = m0 + wm + i*16 + cr + rr;
          const int gn = nh + wn + j*16 + cc;
          S[(long)gm*ldS + gn] = acc[i][j][rr] * mult;
        }
  }
  __syncthreads();   // S fully written, block-visible

  // ---- wave-parallel row softmax: wave wv owns rows m0+wv*32 .. +31 ----
  constexpr int CH = NN / 64;               // cols per lane: 2 or 4
  const int cbase = lane*CH;
  int lim = NN;
  if (lengths){ const int L = lengths[b0 + z1]; lim = (L < NN) ? L : NN; }

  float v[CH], vn[CH], mcur[CH], mnxt[CH];
  {
    float* row0 = S + (long)(m0 + wv*32)*ldS + cbase;
    #pragma unroll
    for (int e=0;e<CH;++e) v[e] = row0[e];
    if (mulP){
      const float* mr = mulP + z1*sMul + (long)(m0 + wv*32)*ldS + cbase;
      #pragma unroll
      for (int e=0;e<CH;++e) mcur[e] = mr[e];
    }
  }
  for (int i = 0; i < 32; ++i){
    if (i < 31){
      float* rn = S + (long)(m0 + wv*32 + i + 1)*ldS + cbase;
      #pragma unroll
      for (int e=0;e<CH;++e) vn[e] = rn[e];
      if (mulP){
        const float* mr = mulP + z1*sMul + (long)(m0 + wv*32 + i + 1)*ldS + cbase;
        #pragma unroll
        for (int e=0;e<CH;++e) mnxt[e] = mr[e];
      }
    }
    float mx = -3.0e38f;
    #pragma unroll
    for (int e=0;e<CH;++e) if (cbase+e < lim) mx = fmaxf(mx, v[e]);
    #pragma unroll
    for (int o=32;o>0;o>>=1) mx = fmaxf(mx, __shfl_xor(mx, o, 64));
    float sm = 0.f;
    #pragma unroll
    for (int e=0;e<CH;++e){
      v[e] = (cbase+e < lim) ? __expf(v[e] - mx) : 0.f;
      sm += v[e];
    }
    #pragma unroll
    for (int o=32;o>0;o>>=1) sm += __shfl_xor(sm, o, 64);
    const float inv = 1.f / sm;
    float* row = S + (long)(m0 + wv*32 + i)*ldS + cbase;
    if (mulP){
      #pragma unroll
      for (int e=0;e<CH;++e) row[e] = v[e]*inv*mcur[e];
    } else {
      #pragma unroll
      for (int e=0;e<CH;++e) row[e] = v[e]*inv;
    }
    #pragma unroll
    for (int e=0;e<CH;++e){ v[e] = vn[e]; mcur[e] = mnxt[e]; }
  }
}

// ---------------- hg chunk init (pair out) ----------------
__global__ void build_hg(const void* __restrict__ src, const short* __restrict__ Ru, long loW,
                         short* __restrict__ hg, long loH, const int* __restrict__ flag, int b0){
  const int t = blockIdx.x, bl = blockIdx.y, se = threadIdx.x;  // block 128
  const int f32 = *flag;
  const float s = rdIn(src, ((long)t*B_ + (b0+bl))*(2*SE_) + se, f32);
  const long o = ((long)bl*SE_ + se)*1024 + t*4;
  #pragma unroll
  for (int j=0;j<4;++j){
    const float v = fmaxf(s * prd(Ru, se*4+j, loW), 0.f);
    short h, l; split1(v, h, l);
    hg[o+j] = h; hg[o+j+loH] = l;
  }
}

// ---------------- xx chunk build (pair in/out) ----------------
__global__ void build_xx(const short* __restrict__ hg, long loH,
                         const short* __restrict__ times, long loW,
                         short* __restrict__ xx, long loX, int b0, int G){
  const int blk = blockIdx.x;          // t*G + bl
  const int t = blk / G, bl = blk % G, b = b0 + bl;
  const int tid = threadIdx.x;
  const float tm = prd(times, (long)t*B_ + b, loW);
  for (int c = tid; c < D_MODEL_; c += 256){
    float v;
    if (c < SE_*4){
      v = prd(hg, ((long)bl*SE_ + (c>>2))*1024 + t*4 + (c&3), loH);
    } else {
      const int p = c - SE_*4;
      const int i = p & 7;
      const float ts = exp2f(8.0f * (float)i / 7.0f);
      const float st = tm / ts;
      v = (p < 8) ? sinf(st) : cosf(st);
    }
    short h, l; split1(v, h, l);
    const long o = ((long)t*B_ + b)*D_MODEL_ + c;
    xx[o] = h; xx[o+loX] = l;
  }
}

// ---------------- LN body (row = 528, pairs) ----------------
__device__ __forceinline__ void ln_body_p(short* px, long loX, const short* pr, long loR,
                                          const short* g, const short* bb, long loW, int tid){
  const float x0 = prd(px,tid,loX)     + prd(pr,tid,loR);
  const float x1 = prd(px,tid+256,loX) + prd(pr,tid+256,loR);
  const float x2 = (tid < 16) ? (prd(px,tid+512,loX) + prd(pr,tid+512,loR)) : 0.f;
  __shared__ float rs[256], rq[256];
  rs[tid] = x0 + x1 + x2;
  rq[tid] = x0*x0 + x1*x1 + x2*x2;
  __syncthreads();
  for (int h = 128; h > 0; h >>= 1){
    if (tid < h){ rs[tid] += rs[tid+h]; rq[tid] += rq[tid+h]; }
    __syncthreads();
  }
  const float mean = rs[0] * (1.0f/528.0f);
  const float var  = rq[0] * (1.0f/528.0f) - mean*mean;
  const float inv = rsqrtf(var + 1e-5f);
  short h, l;
  split1((x0-mean)*inv*prd(g,tid,loW) + prd(bb,tid,loW), h, l);
  px[tid] = h; px[tid+loX] = l;
  split1((x1-mean)*inv*prd(g,tid+256,loW) + prd(bb,tid+256,loW), h, l);
  px[tid+256] = h; px[tid+256+loX] = l;
  if (tid < 16){
    split1((x2-mean)*inv*prd(g,tid+512,loW) + prd(bb,tid+512,loW), h, l);
    px[tid+512] = h; px[tid+512+loX] = l;
  }
}

__global__ __launch_bounds__(256) void ln_res_attn(short* __restrict__ xx, long loX,
    const short* __restrict__ res, long loR,
    const short* __restrict__ g, const short* __restrict__ bb, long loW, int b0){
  const int z = blockIdx.x >> 8, t = blockIdx.x & 255;
  short* px = xx + ((long)t*B_ + b0 + z)*D_MODEL_;
  const short* pr = res + (long)blockIdx.x*D_MODEL_;
  ln_body_p(px, loX, pr, loR, g, bb, loW, threadIdx.x);
}

__global__ __launch_bounds__(256) void ln_res_rows(short* __restrict__ xx, long loX,
    const short* __restrict__ res, long loR,
    const short* __restrict__ g, const short* __restrict__ bb, long loW, int r0){
  short* px = xx + ((long)r0 + blockIdx.x)*D_MODEL_;
  const short* pr = res + (long)blockIdx.x*D_MODEL_;
  ln_body_p(px, loX, pr, loR, g, bb, loW, threadIdx.x);
}

// ---------------- masked mean pool (pair in/out) ----------------
__global__ void pool_k(const short* __restrict__ xx, long loX, const int* __restrict__ len,
                       short* __restrict__ pooled, long loP){
  const int b = blockIdx.y;
  const int c = blockIdx.x*256 + threadIdx.x;
  if (c >= D_MODEL_) return;
  const int L = len[b];
  float s = 0.f;
  for (int t = 0; t < L; ++t) s += prd(xx, ((long)t*B_ + b)*D_MODEL_ + c, loX);
  short h, l; split1(s / (float)(L + 1), h, l);
  pooled[(long)b*D_FINAL_ + c] = h;
  pooled[(long)b*D_FINAL_ + c + loP] = l;
}

// ---------------- logits (pair in, out dtype per flag) ----------------
__global__ void logits_k(const short* __restrict__ hid, long loH,
                         const short* __restrict__ W2, const short* __restrict__ b2, long loW,
                         void* __restrict__ out, const int* __restrict__ flag){
  const int z = blockIdx.x;            // b*2 + c
  const int b = z >> 1, c = z & 1;
  const int lane = threadIdx.x;        // 64
  float s = 0.f;
  for (int k = lane; k < D_FINAL_; k += 64)
    s += prd(hid, (long)b*D_FINAL_ + k, loH) * prd(W2, (long)c*D_FINAL_ + k, loW);
  #pragma unroll
  for (int o = 32; o > 0; o >>= 1) s += __shfl_down(s, o, 64);
  if (lane == 0){
    const float r = s + prd(b2, c, loW);
    if (*flag) ((float*)out)[z] = r;
    else       ((bf16*)out)[z] = __float2bfloat16(r);
  }
}

// =======================================================================
// Arena identical to round 9 (peak ~155 MiB, proven cap 167.3 MiB).
// =======================================================================
extern "C" void kernel_launch(void* const* d_in, const int* in_sizes, int n_in,
                              void* d_out, int out_size, void* d_ws, size_t ws_size,
                              hipStream_t stream) {
  const int* lengths = (const int*)d_in[2];
  char* ws = (char*)d_ws;
  const size_t KB = 1024;

  short* wtsH = (short*)ws;
  int* flag = (int*)(ws + 47500*KB);
  short* xxH = (short*)(ws + 48000*KB);
  const long loXX = 17301504;
  char* SC = ws + 115600*KB;

  short* hgA = (short*)(SC + 0*KB);      const long loHG = 2097152;
  short* hgB = (short*)(SC + 8192*KB);
  short* qkc = (short*)(SC + 16384*KB);  const long loQK1 = 4194304;
  short* VtS = (short*)(SC + 32768*KB);  const long loVT1 = 2097152;
  float* S0c = (float*)(SC + 40960*KB);
  float* S1c = (float*)(SC + 41984*KB);
  short* qkb = (short*)(SC + 0*KB);      const long loQK2 = 4325376;
  short* o_c = (short*)(SC + 0*KB);      const long loOC  = 2162688;
  short* pjb = (short*)(SC + 8448*KB);   const long loPJ  = 2162688;
  short* vtb = (short*)(SC + 16896*KB);  const long loVT2 = 2162688;
  float* att = (float*)(SC + 25344*KB);
  short* ff1 = (short*)(SC + 0*KB);      const long loFF  = 4194304;
  short* pj2 = (short*)(SC + 16896*KB);  const long loPJ2 = 4325376;
  short* pooled = (short*)(SC + 0*KB);   const long loPO  = 133120;
  short* hid    = (short*)(SC + 1024*KB);

  CvtTab tb; long cur = 0; int nb = 0; int e = 0;
  auto add = [&](int idx, long so, long n)->long{
    tb.src[e] = d_in[idx]; tb.srcOff[e] = so; tb.dstOff[e] = cur;
    tb.n[e] = (int)n; tb.bstart[e] = nb;
    nb += (int)((n + 255)/256); cur += n; e++;
    return cur - n;
  };
  const long oT  = add(1,0,32768);
  const long oSt = add(3,0,8192);
  const long oRu = add(4,0,512);
  const long oSW = add(5,0,32768);
  const long oSb = add(6,0,512);
  long oQKSV[2], oBQ[2];
  for (int l = 0; l < 2; ++l){
    oQKSV[l] = add(7, (long)l*1048576, 1048576);
    add(8,  (long)l*1048576, 1048576);
    add(13, (long)l*1048576, 1048576);
    add(9,  (long)l*1048576, 1048576);
  }
  for (int l = 0; l < 2; ++l){
    oBQ[l] = add(10, (long)l*1024, 1024);
    add(11, (long)l*1024, 1024);
    add(14, (long)l*1024, 1024);
    add(12, (long)l*1024, 1024);
  }
  const long oWqkv = add(15,0,1672704);
  const long obqkv = add(16,0,3168);
  const long oWo = add(17,0,557568);
  const long obo = add(18,0,1056);
  const long oW1 = add(19,0,135168);
  const long ob1 = add(20,0,256);
  const long oW2 = add(21,0,135168);
  const long ob2 = add(22,0,1056);
  const long og1 = add(23,0,1056);
  const long obb1 = add(24,0,1056);
  const long og2 = add(25,0,1056);
  const long obb2 = add(26,0,1056);
  const long oM1 = add(27,0,1081600);
  const long oM1b = add(28,0,1040);
  const long oM2 = add(29,0,2080);
  const long oM2b = add(30,0,2);
  tb.cnt = e;
  const long loW = (cur + 7) & ~7L;

  detect_k<<<1,256,0,stream>>>(d_in[0], flag);
  cvt_all<<<nb,256,0,stream>>>(tb, wtsH, loW, flag);

  const Route RZ{nullptr,0,0,0,0,0,0};

  // ================= stage 1: propagation (16-batch chunks) =================
  const int G1 = 16;
  for (int b0 = 0; b0 < B_; b0 += G1){
    build_hg<<<dim3(T_, G1), 128, 0, stream>>>(d_in[0], wtsH+oRu, loW, hgA, loHG, flag, b0);
    short* curb = hgA; short* nxtb = hgB;
    for (int l = 0; l < 2; ++l){
      float* S = (l == 0) ? S0c : S1c;
      {
        Route q{qkc, 2048, loQK1, 0, 0, 2048, 0};
        Route s{nxtb, 1024, loHG, 0, 0, 3072, 0};
        Route v{VtS, 2048, loVT1, 0, 0, 4096, 1};
        gemm_s<false,true,16><<<dim3(32,16,1),256,0,stream>>>(
            curb, loHG, wtsH+oQKSV[l], loW, wtsH+oBQ[l], loW,
            2048, 4096, 1024, 1024, 1024,
            1, 0,0,0,0, 0, 3, q, s, v, 1.f);
      }
      gemm_sm<128,true,16><<<dim3(1,1,G1),256,0,stream>>>(
          qkc, loQK1, qkc+1024, loQK1,
          1024, 2048, 2048,
          G1, 262144, 262144, 0, 0,
          S, 16384, 0, 128,
          0.03125f, nullptr, 0,
          (l == 1) ? S0c : nullptr, 16384);
      {
        Route c{nxtb, 1024, loHG, 131072, 0, 1024, 2};
        gemm_s<true,true,16><<<dim3(8,1,G1),256,0,stream>>>(
            S, 0, VtS, loVT1, nullptr, 0,
            128, 1024, 128, 128, 2048,
            G1, 16384, 128, 0, 0, 0, 1, c, RZ, RZ, 1.f);
      }
      short* t_ = curb; curb = nxtb; nxtb = t_;
    }
    build_xx<<<T_*G1,256,0,stream>>>(curb, loHG, wtsH+oT, loW, xxH, loXX, b0, G1);
  }

  // ================= stage 2: transformer (16-batch chunks) =================
  const float iscl = 1.0f / sqrtf((float)HD_);
  const int G2 = 16;
  for (int l = 0; l < 2; ++l){
    const long wqkv = oWqkv + (long)l*836352;
    const long bqkv = obqkv + (long)l*1584;
    for (int b0 = 0; b0 < B_; b0 += G2){
      {
        Route qk{qkb, 1056, loQK2, 270336, 0, 1056, 0};
        Route v{vtb, 256, loVT2, 135168, 0, 1584, 1};
        gemm_s<false,true,16><<<dim3(13,2,G2),256,0,stream>>>(
            xxH + (long)b0*D_MODEL_, loXX, wtsH+wqkv, loW, wtsH+bqkv, loW,
            256, 1584, 528, (long)B_*D_MODEL_, 528,
            G2, 528, 0, 0, 0, 0, 2, qk, v, RZ, 1.f);
      }
      gemm_sm<256,false,8><<<dim3(1,2,G2*NH_),256,0,stream>>>(
          qkb, loQK2, qkb+528, loQK2,
          132, 1056, 1056,
          G2, 270336, 270336, 132, 132,
          att, 262144, 65536, 256,
          iscl, lengths, b0, nullptr, 0);
      {
        Route c{o_c, 528, loOC, 135168, 132, HD_, 0};
        gemm_s<true,true,16><<<dim3(2,2,G2*NH_),256,0,stream>>>(
            att, 0, vtb, loVT2, nullptr, 0,
            256, HD_, 256, 256, 256,
            G2, 262144, 135168, 65536, 33792, 0, 1, c, RZ, RZ, 1.f);
      }
      {
        Route c{pjb, 528, loPJ, 135168, 0, 528, 0};
        gemm_s<false,true,16><<<dim3(5,2,G2),256,0,stream>>>(
            o_c, loOC, wtsH+oWo+(long)l*278784, loW, wtsH+obo+(long)l*528, loW,
            256, 528, 528, 528, 528,
            G2, 135168, 0, 0, 0, 0, 1, c, RZ, RZ, 1.f);
      }
      ln_res_attn<<<G2*256,256,0,stream>>>(xxH, loXX, pjb, loPJ,
          wtsH+og1+(long)l*528, wtsH+obb1+(long)l*528, loW, b0);
    }
    {
      Route c{ff1, 128, loFF, 0, 0, 128, 0};
      gemm_s<false,true,16><<<dim3(1,256,1),256,0,stream>>>(
          xxH, loXX, wtsH+oW1+(long)l*67584, loW, wtsH+ob1+(long)l*128, loW,
          32768, 128, 528, 528, 528,
          1, 0,0,0,0, 1, 1, c, RZ, RZ, 1.f);
    }
    for (int r0 = 0; r0 < 32768; r0 += 8192){
      Route c{pj2, 528, loPJ2, 0, 0, 528, 0};
      gemm_s<false,true,16><<<dim3(5,64,1),256,0,stream>>>(
          ff1 + (long)r0*128, loFF, wtsH+oW2+(long)l*67584, loW, wtsH+ob2+(long)l*528, loW,
          8192, 528, 128, 128, 128,
          1, 0,0,0,0, 0, 1, c, RZ, RZ, 1.f);
      ln_res_rows<<<8192,256,0,stream>>>(xxH, loXX, pj2, loPJ2,
          wtsH+og2+(long)l*528, wtsH+obb2+(long)l*528, loW, r0);
    }
  }

  // ================= stage 3: pool + MLP head =================
  pool_k<<<dim3(3,B_),256,0,stream>>>(xxH, loXX, lengths, pooled, loPO);
  {
    Route c{pooled + D_MODEL_, 1040, loPO, 0, 0, 512, 0};
    gemm_s<false,true,16><<<dim3(4,1,1),256,0,stream>>>(
        wtsH+oSt, loW, wtsH+oSW, loW, wtsH+oSb, loW,
        128, 512, 64, 64, 64,
        1, 0,0,0,0, 0, 1, c, RZ, RZ, 1.f);
  }
  {
    Route c{hid, 1040, loPO, 0, 0, 1040, 0};
    gemm_s<false,true,16><<<dim3(9,1,1),256,0,stream>>>(
        pooled, loPO, wtsH+oM1, loW, wtsH+oM1b, loW,
        128, 1040, 1040, 1040, 1040,
        1, 0,0,0,0, 1, 1, c, RZ, RZ, 1.f);
  }
  logits_k<<<B_*2,64,0,stream>>>(hid, loPO, wtsH+oM2, wtsH+oM2b, loW, d_out, flag);
}

// Round 11
// 7114.255 us; speedup vs baseline: 1.9318x; 1.1651x over previous
//
#include <hip/hip_runtime.h>
#include <hip/hip_bf16.h>
#include <math.h>

#define SE_    128
#define T_     256
#define B_     128
#define NH_    4
#define HD_    132
#define D_MODEL_ 528
#define D_FINAL_ 1040
#define D_FF_  128

typedef __hip_bfloat16 bf16;
typedef __attribute__((ext_vector_type(8))) short bf16x8v;
typedef __attribute__((ext_vector_type(4))) float f32x4;

__device__ __forceinline__ float bfb(unsigned short u){
  union { float f; unsigned int i; } c; c.i = ((unsigned int)u) << 16; return c.f;
}
__device__ __forceinline__ unsigned short bfr(float x){
  unsigned u = __builtin_bit_cast(unsigned, x);
  unsigned r = (u + 0x7FFFu + ((u >> 16) & 1u)) >> 16;
  return (unsigned short)r;
}
__device__ __forceinline__ void split1(float x, short& h, short& l){
  const unsigned short hu = bfr(x);
  const unsigned short lu = bfr(x - bfb(hu));
  h = (short)hu; l = (short)lu;
}
__device__ __forceinline__ float prd(const short* p, long i, long lo){
  return bfb((unsigned short)p[i]) + bfb((unsigned short)p[i+lo]);
}
__device__ __forceinline__ float rdIn(const void* p, long i, int f32){
  return f32 ? ((const float*)p)[i] : __bfloat162float(((const bf16*)p)[i]);
}

// ---------------- dtype detect: 1 = f32 inputs, 0 = bf16 ----------------
__global__ void detect_k(const void* __restrict__ src, int* __restrict__ flag){
  const unsigned int* p = (const unsigned int*)src;
  int bad = 0;
  for (int i = threadIdx.x; i < 4096; i += 256){
    const unsigned int lo = p[i] & 0xFFFFu;
    const unsigned int e = (lo >> 7) & 0xFFu;
    if (e >= 0xC0u) bad++;
  }
  __shared__ int red[256];
  red[threadIdx.x] = bad; __syncthreads();
  for (int h = 128; h > 0; h >>= 1){
    if (threadIdx.x < h) red[threadIdx.x] += red[threadIdx.x+h];
    __syncthreads();
  }
  if (threadIdx.x == 0) *flag = (red[0] > 64) ? 1 : 0;
}

// ---------------- mega conversion: all weights -> hi/lo bf16 planes ----------------
#define MAXE 40
struct CvtTab {
  const void* src[MAXE];
  long srcOff[MAXE];
  long dstOff[MAXE];
  int n[MAXE];
  int bstart[MAXE];
  int cnt;
};
__global__ void cvt_all(CvtTab tb, short* __restrict__ wts, long loW, const int* __restrict__ flag){
  const int b = blockIdx.x;
  int e = 0;
  for (int i = 1; i < tb.cnt; ++i) if (tb.bstart[i] <= b) e = i;
  const long i = (long)(b - tb.bstart[e])*256 + threadIdx.x;
  if (i >= tb.n[e]) return;
  const float v = rdIn(tb.src[e], tb.srcOff[e] + i, *flag);
  short h, l; split1(v, h, l);
  wts[tb.dstOff[e] + i] = h;
  wts[tb.dstOff[e] + i + loW] = l;
}

// =======================================================================
// Swizzled LDS tile layout: plane = short[128*32]; row r holds K-chunk q
// (8 shorts) at LDS chunk c = q ^ s(r), s(r) = (r&3)^((r>>2)&3).
// Worst-case 2-way bank aliasing on ds_read_b128 (free, m136).
// =======================================================================
__device__ __forceinline__ int swz(int r){ return (r&3) ^ ((r>>2)&3); }

// ---- DMA staging: global_load_lds width 16, both planes ----
__device__ __forceinline__ void gllstage_pair(const short* __restrict__ g, long lo, long ld,
    int kb, int row_g0, int rmax, int tid, short* Lh, short* Ll){
  const int w = tid>>6, ln = tid&63;
  #pragma unroll
  for (int inst=0; inst<2; ++inst){
    const int r = (w*2+inst)*16 + (ln>>2);
    int gr = row_g0 + r; if (gr > rmax) gr = rmax;
    const int q = (ln&3) ^ (((ln>>2)&3) ^ ((ln>>4)&3));   // = (ln&3) ^ s(r)
    const short* p = g + (long)gr*ld + kb + q*8;
    short* dh = Lh + (w*2+inst)*512;
    short* dl = Ll + (w*2+inst)*512;
    __builtin_amdgcn_global_load_lds(
        (const __attribute__((address_space(1))) void*)p,
        (__attribute__((address_space(3))) void*)dh, 16, 0, 0);
    __builtin_amdgcn_global_load_lds(
        (const __attribute__((address_space(1))) void*)(p + lo),
        (__attribute__((address_space(3))) void*)dl, 16, 0, 0);
  }
}

// ---- register staging (tails / unaligned / f32-split), same layout ----
__device__ __forceinline__ void regstage_pair(const short* __restrict__ g, long lo, long ld,
    int kb, int K, int row_g0, int rmax, int tid, short* Lh, short* Ll){
  const int r = tid>>1;
  int gr = row_g0 + r; if (gr > rmax) gr = rmax;
  const int s = swz(r);
  #pragma unroll
  for (int cq=0;cq<2;++cq){
    const int q = (tid&1)*2 + cq;
    const int k0 = kb + q*8;
    short bh[8], bl[8];
    const short* p = g + (long)gr*ld + k0;
    if (k0 + 8 <= K){
      *(int2*)(bh)   = *(const int2*)(p);      *(int2*)(bh+4) = *(const int2*)(p+4);
      *(int2*)(bl)   = *(const int2*)(p+lo);   *(int2*)(bl+4) = *(const int2*)(p+lo+4);
    } else {
      #pragma unroll
      for (int e=0;e<8;++e){
        const bool ok = (k0+e) < K;
        bh[e] = ok ? p[e] : (short)0;
        bl[e] = ok ? p[lo+e] : (short)0;
      }
    }
    const int c = q ^ s;
    *(int4*)&Lh[r*32 + c*8] = *(const int4*)bh;
    *(int4*)&Ll[r*32 + c*8] = *(const int4*)bl;
  }
}

__device__ __forceinline__ void regstage_f32(const float* __restrict__ g, long ld,
    int kb, int K, int row_g0, int rmax, int tid, short* Lh, short* Ll){
  const int r = tid>>1;
  int gr = row_g0 + r; if (gr > rmax) gr = rmax;
  const int s = swz(r);
  #pragma unroll
  for (int cq=0;cq<2;++cq){
    const int q = (tid&1)*2 + cq;
    const int k0 = kb + q*8;
    short bh[8], bl[8];
    const float* p = g + (long)gr*ld + k0;
    if (k0 + 8 <= K){
      float f[8];
      *(float4*)(f)   = *(const float4*)(p);
      *(float4*)(f+4) = *(const float4*)(p+4);
      #pragma unroll
      for (int e=0;e<8;++e) split1(f[e], bh[e], bl[e]);
    } else {
      #pragma unroll
      for (int e=0;e<8;++e){
        const float v = (k0+e < K) ? p[e] : 0.f;
        split1(v, bh[e], bl[e]);
      }
    }
    const int c = q ^ s;
    *(int4*)&Lh[r*32 + c*8] = *(const int4*)bh;
    *(int4*)&Ll[r*32 + c*8] = *(const int4*)bl;
  }
}

// ---- swizzled frag read ----
__device__ __forceinline__ void rd_frags(const short* Lh, const short* Ll,
                                         int wbase, int fr, int qlog,
                                         bf16x8v ah[4], bf16x8v al[4]){
  const int cs = (qlog ^ ((fr&3) ^ ((fr>>2)&3))) * 8;
  #pragma unroll
  for (int i=0;i<4;++i){
    const int r_ = wbase + i*16 + fr;
    ah[i] = *reinterpret_cast<const bf16x8v*>(&Lh[r_*32 + cs]);
    al[i] = *reinterpret_cast<const bf16x8v*>(&Ll[r_*32 + cs]);
  }
}

// =======================================================================
// bf16x3 emulated-f32 NT GEMM: A,B staged to LDS via global_load_lds DMA
// (register path for K-tails / f32-A), routed pair epilogue.
// =======================================================================
struct Route { short* C; long ldc; long lo; long sC; long sC2; int nEnd; int fl; }; // fl: 1=trans 2=acc

template<bool SPLITA, bool GLL>
__global__ __launch_bounds__(256, 2) void gemm_s(
    const void* __restrict__ Ag, long loA,
    const short* __restrict__ Bg, long loB,
    const short* __restrict__ bias, long loBias,
    int M, int N, int K, long lda, long ldb,
    int nz1, long sA, long sB, long sA2, long sB2,
    int relu, int nroute, Route r0, Route r1, Route r2, float mult)
{
  __shared__ short As_h[128*32], As_l[128*32], Bs_h[128*32], Bs_l[128*32];
  const int tid = threadIdx.x;
  const int z1 = blockIdx.z % nz1, z2 = blockIdx.z / nz1;
  const int m0 = blockIdx.y*128, n0 = blockIdx.x*128;
  const void* A;
  if (SPLITA) A = (const void*)((const float*)Ag + z1*sA + z2*sA2);
  else        A = (const void*)((const short*)Ag + z1*sA + z2*sA2);
  const short* B = Bg + z1*sB + z2*sB2;
  short* Cb0 = r0.C + z1*r0.sC + z2*r0.sC2;
  short* Cb1 = (nroute > 1) ? (r1.C + z1*r1.sC + z2*r1.sC2) : nullptr;
  short* Cb2 = (nroute > 2) ? (r2.C + z1*r2.sC + z2*r2.sC2) : nullptr;

  const int lane = tid & 63, wv = tid >> 6;
  const int wm = (wv >> 1)*64, wn = (wv & 1)*64;
  const int fr = lane & 15, qlog = lane >> 4;

  f32x4 acc[4][4] = {};
  for (int kb = 0; kb < K; kb += 32){
    const bool tail = (kb + 32 > K);
    if (SPLITA) regstage_f32((const float*)A, lda, kb, K, m0, M-1, tid, As_h, As_l);
    else if (GLL && !tail) gllstage_pair((const short*)A, loA, lda, kb, m0, M-1, tid, As_h, As_l);
    else regstage_pair((const short*)A, loA, lda, kb, K, m0, M-1, tid, As_h, As_l);
    if (GLL && !tail) gllstage_pair(B, loB, ldb, kb, n0, N-1, tid, Bs_h, Bs_l);
    else regstage_pair(B, loB, ldb, kb, K, n0, N-1, tid, Bs_h, Bs_l);
    __syncthreads();

    bf16x8v ah[4], al[4], bh[4], bl[4];
    rd_frags(As_h, As_l, wm, fr, qlog, ah, al);
    rd_frags(Bs_h, Bs_l, wn, fr, qlog, bh, bl);
    #pragma unroll
    for (int j=0;j<4;++j)
      #pragma unroll
      for (int i=0;i<4;++i){
        acc[i][j] = __builtin_amdgcn_mfma_f32_16x16x32_bf16(ah[i], bh[j], acc[i][j], 0,0,0);
        acc[i][j] = __builtin_amdgcn_mfma_f32_16x16x32_bf16(ah[i], bl[j], acc[i][j], 0,0,0);
        acc[i][j] = __builtin_amdgcn_mfma_f32_16x16x32_bf16(al[i], bh[j], acc[i][j], 0,0,0);
      }
    __syncthreads();
  }

  const int cr = (lane >> 4)*4, cc = lane & 15;
  #pragma unroll
  for (int i=0;i<4;++i){
    #pragma unroll
    for (int j=0;j<4;++j){
      #pragma unroll
      for (int rr=0;rr<4;++rr){
        const int gm = m0 + wm + i*16 + cr + rr;
        const int gn = n0 + wn + j*16 + cc;
        if (gm < M && gn < N){
          float v = acc[i][j][rr] * mult;
          if (bias) v += prd(bias, gn, loBias);
          if (relu) v = fmaxf(v, 0.f);
          short* Cp; long ldc, lo; int fl, cn;
          if (nroute > 1 && gn >= r0.nEnd){
            if (nroute > 2 && gn >= r1.nEnd){ Cp=Cb2; ldc=r2.ldc; lo=r2.lo; fl=r2.fl; cn=gn-r1.nEnd; }
            else                            { Cp=Cb1; ldc=r1.ldc; lo=r1.lo; fl=r1.fl; cn=gn-r0.nEnd; }
          } else                            { Cp=Cb0; ldc=r0.ldc; lo=r0.lo; fl=r0.fl; cn=gn; }
          const long idx = (fl & 1) ? ((long)cn*ldc + gm) : ((long)gm*ldc + cn);
          if (fl & 2) v += prd(Cp, idx, lo);
          short h, l; split1(v, h, l);
          Cp[idx] = h; Cp[idx + lo] = l;
        }
      }
    }
  }
}

// =======================================================================
// scores GEMM + fused wave-parallel row softmax. GLL=true requires all
// bases 16B-aligned (stage-1); GLL=false uses register staging (stage-2).
// =======================================================================
template<int NN, bool GLL>
__global__ __launch_bounds__(256, 2) void gemm_sm(
    const short* __restrict__ Ag, long loA, const short* __restrict__ Bg, long loB,
    int K, long lda, long ldb,
    int nz1, long sA, long sB, long sA2, long sB2,
    float* __restrict__ Sg, long sS, long sS2, int ldS,
    float mult, const int* __restrict__ lengths, int b0,
    const float* __restrict__ mulP, long sMul)
{
  __shared__ short As_h[128*32], As_l[128*32], Bs_h[128*32], Bs_l[128*32];
  const int tid = threadIdx.x;
  const int z1 = blockIdx.z % nz1, z2 = blockIdx.z / nz1;
  const int m0 = blockIdx.y*128;
  const short* A = Ag + z1*sA + z2*sA2;
  const short* B = Bg + z1*sB + z2*sB2;
  float* S = Sg + z1*sS + z2*sS2;

  const int lane = tid & 63, wv = tid >> 6;
  const int wm = (wv >> 1)*64, wn = (wv & 1)*64;
  const int fr = lane & 15, qlog = lane >> 4;
  const int cr = (lane >> 4)*4, cc = lane & 15;

  for (int nh = 0; nh < NN; nh += 128){
    f32x4 acc[4][4] = {};
    for (int kb = 0; kb < K; kb += 32){
      const bool tail = (kb + 32 > K);
      if (GLL && !tail){
        gllstage_pair(A, loA, lda, kb, m0, m0+127, tid, As_h, As_l);
        gllstage_pair(B, loB, ldb, kb, nh, nh+127, tid, Bs_h, Bs_l);
      } else {
        regstage_pair(A, loA, lda, kb, K, m0, m0+127, tid, As_h, As_l);
        regstage_pair(B, loB, ldb, kb, K, nh, nh+127, tid, Bs_h, Bs_l);
      }
      __syncthreads();
      bf16x8v ah[4], al[4], bh[4], bl[4];
      rd_frags(As_h, As_l, wm, fr, qlog, ah, al);
      rd_frags(Bs_h, Bs_l, wn, fr, qlog, bh, bl);
      #pragma unroll
      for (int j=0;j<4;++j)
        #pragma unroll
        for (int i=0;i<4;++i){
          acc[i][j] = __builtin_amdgcn_mfma_f32_16x16x32_bf16(ah[i], bh[j], acc[i][j], 0,0,0);
          acc[i][j] = __builtin_amdgcn_mfma_f32_16x16x32_bf16(ah[i], bl[j], acc[i][j], 0,0,0);
          acc[i][j] = __builtin_amdgcn_mfma_f32_16x16x32_bf16(al[i], bh[j], acc[i][j], 0,0,0);
        }
      __syncthreads();
    }
    #pragma unroll
    for (int i=0;i<4;++i)
      #pragma unroll
      for (int j=0;j<4;++j)
        #pragma unroll
        for (int rr=0;rr<4;++rr){
          const int gm = m0 + wm + i*16 + cr + rr;
          const int gn = nh + wn + j*16 + cc;
          S[(long)gm*ldS + gn] = acc[i][j][rr] * mult;
        }
  }
  __syncthreads();   // S fully written, block-visible

  // ---- wave-parallel row softmax: wave wv owns rows m0+wv*32 .. +31 ----
  constexpr int CH = NN / 64;               // cols per lane: 2 or 4
  const int cbase = lane*CH;
  int lim = NN;
  if (lengths){ const int L = lengths[b0 + z1]; lim = (L < NN) ? L : NN; }

  float v[CH], vn[CH], mcur[CH], mnxt[CH];
  {
    float* row0 = S + (long)(m0 + wv*32)*ldS + cbase;
    #pragma unroll
    for (int e=0;e<CH;++e) v[e] = row0[e];
    if (mulP){
      const float* mr = mulP + z1*sMul + (long)(m0 + wv*32)*ldS + cbase;
      #pragma unroll
      for (int e=0;e<CH;++e) mcur[e] = mr[e];
    }
  }
  for (int i = 0; i < 32; ++i){
    if (i < 31){
      float* rn = S + (long)(m0 + wv*32 + i + 1)*ldS + cbase;
      #pragma unroll
      for (int e=0;e<CH;++e) vn[e] = rn[e];
      if (mulP){
        const float* mr = mulP + z1*sMul + (long)(m0 + wv*32 + i + 1)*ldS + cbase;
        #pragma unroll
        for (int e=0;e<CH;++e) mnxt[e] = mr[e];
      }
    }
    float mx = -3.0e38f;
    #pragma unroll
    for (int e=0;e<CH;++e) if (cbase+e < lim) mx = fmaxf(mx, v[e]);
    #pragma unroll
    for (int o=32;o>0;o>>=1) mx = fmaxf(mx, __shfl_xor(mx, o, 64));
    float sm = 0.f;
    #pragma unroll
    for (int e=0;e<CH;++e){
      v[e] = (cbase+e < lim) ? __expf(v[e] - mx) : 0.f;
      sm += v[e];
    }
    #pragma unroll
    for (int o=32;o>0;o>>=1) sm += __shfl_xor(sm, o, 64);
    const float inv = 1.f / sm;
    float* row = S + (long)(m0 + wv*32 + i)*ldS + cbase;
    if (mulP){
      #pragma unroll
      for (int e=0;e<CH;++e) row[e] = v[e]*inv*mcur[e];
    } else {
      #pragma unroll
      for (int e=0;e<CH;++e) row[e] = v[e]*inv;
    }
    #pragma unroll
    for (int e=0;e<CH;++e){ v[e] = vn[e]; mcur[e] = mnxt[e]; }
  }
}

// ---------------- hg chunk init (pair out) ----------------
__global__ void build_hg(const void* __restrict__ src, const short* __restrict__ Ru, long loW,
                         short* __restrict__ hg, long loH, const int* __restrict__ flag, int b0){
  const int t = blockIdx.x, bl = blockIdx.y, se = threadIdx.x;  // block 128
  const int f32 = *flag;
  const float s = rdIn(src, ((long)t*B_ + (b0+bl))*(2*SE_) + se, f32);
  const long o = ((long)bl*SE_ + se)*1024 + t*4;
  #pragma unroll
  for (int j=0;j<4;++j){
    const float v = fmaxf(s * prd(Ru, se*4+j, loW), 0.f);
    short h, l; split1(v, h, l);
    hg[o+j] = h; hg[o+j+loH] = l;
  }
}

// ---------------- xx chunk build (pair in/out) ----------------
__global__ void build_xx(const short* __restrict__ hg, long loH,
                         const short* __restrict__ times, long loW,
                         short* __restrict__ xx, long loX, int b0, int G){
  const int blk = blockIdx.x;          // t*G + bl
  const int t = blk / G, bl = blk % G, b = b0 + bl;
  const int tid = threadIdx.x;
  const float tm = prd(times, (long)t*B_ + b, loW);
  for (int c = tid; c < D_MODEL_; c += 256){
    float v;
    if (c < SE_*4){
      v = prd(hg, ((long)bl*SE_ + (c>>2))*1024 + t*4 + (c&3), loH);
    } else {
      const int p = c - SE_*4;
      const int i = p & 7;
      const float ts = exp2f(8.0f * (float)i / 7.0f);
      const float st = tm / ts;
      v = (p < 8) ? sinf(st) : cosf(st);
    }
    short h, l; split1(v, h, l);
    const long o = ((long)t*B_ + b)*D_MODEL_ + c;
    xx[o] = h; xx[o+loX] = l;
  }
}

// ---------------- LN body (row = 528, pairs) ----------------
__device__ __forceinline__ void ln_body_p(short* px, long loX, const short* pr, long loR,
                                          const short* g, const short* bb, long loW, int tid){
  const float x0 = prd(px,tid,loX)     + prd(pr,tid,loR);
  const float x1 = prd(px,tid+256,loX) + prd(pr,tid+256,loR);
  const float x2 = (tid < 16) ? (prd(px,tid+512,loX) + prd(pr,tid+512,loR)) : 0.f;
  __shared__ float rs[256], rq[256];
  rs[tid] = x0 + x1 + x2;
  rq[tid] = x0*x0 + x1*x1 + x2*x2;
  __syncthreads();
  for (int h = 128; h > 0; h >>= 1){
    if (tid < h){ rs[tid] += rs[tid+h]; rq[tid] += rq[tid+h]; }
    __syncthreads();
  }
  const float mean = rs[0] * (1.0f/528.0f);
  const float var  = rq[0] * (1.0f/528.0f) - mean*mean;
  const float inv = rsqrtf(var + 1e-5f);
  short h, l;
  split1((x0-mean)*inv*prd(g,tid,loW) + prd(bb,tid,loW), h, l);
  px[tid] = h; px[tid+loX] = l;
  split1((x1-mean)*inv*prd(g,tid+256,loW) + prd(bb,tid+256,loW), h, l);
  px[tid+256] = h; px[tid+256+loX] = l;
  if (tid < 16){
    split1((x2-mean)*inv*prd(g,tid+512,loW) + prd(bb,tid+512,loW), h, l);
    px[tid+512] = h; px[tid+512+loX] = l;
  }
}

__global__ __launch_bounds__(256) void ln_res_attn(short* __restrict__ xx, long loX,
    const short* __restrict__ res, long loR,
    const short* __restrict__ g, const short* __restrict__ bb, long loW, int b0){
  const int z = blockIdx.x >> 8, t = blockIdx.x & 255;
  short* px = xx + ((long)t*B_ + b0 + z)*D_MODEL_;
  const short* pr = res + (long)blockIdx.x*D_MODEL_;
  ln_body_p(px, loX, pr, loR, g, bb, loW, threadIdx.x);
}

__global__ __launch_bounds__(256) void ln_res_rows(short* __restrict__ xx, long loX,
    const short* __restrict__ res, long loR,
    const short* __restrict__ g, const short* __restrict__ bb, long loW, int r0){
  short* px = xx + ((long)r0 + blockIdx.x)*D_MODEL_;
  const short* pr = res + (long)blockIdx.x*D_MODEL_;
  ln_body_p(px, loX, pr, loR, g, bb, loW, threadIdx.x);
}

// ---------------- masked mean pool (pair in/out) ----------------
__global__ void pool_k(const short* __restrict__ xx, long loX, const int* __restrict__ len,
                       short* __restrict__ pooled, long loP){
  const int b = blockIdx.y;
  const int c = blockIdx.x*256 + threadIdx.x;
  if (c >= D_MODEL_) return;
  const int L = len[b];
  float s = 0.f;
  for (int t = 0; t < L; ++t) s += prd(xx, ((long)t*B_ + b)*D_MODEL_ + c, loX);
  short h, l; split1(s / (float)(L + 1), h, l);
  pooled[(long)b*D_FINAL_ + c] = h;
  pooled[(long)b*D_FINAL_ + c + loP] = l;
}

// ---------------- logits (pair in, out dtype per flag) ----------------
__global__ void logits_k(const short* __restrict__ hid, long loH,
                         const short* __restrict__ W2, const short* __restrict__ b2, long loW,
                         void* __restrict__ out, const int* __restrict__ flag){
  const int z = blockIdx.x;            // b*2 + c
  const int b = z >> 1, c = z & 1;
  const int lane = threadIdx.x;        // 64
  float s = 0.f;
  for (int k = lane; k < D_FINAL_; k += 64)
    s += prd(hid, (long)b*D_FINAL_ + k, loH) * prd(W2, (long)c*D_FINAL_ + k, loW);
  #pragma unroll
  for (int o = 32; o > 0; o >>= 1) s += __shfl_down(s, o, 64);
  if (lane == 0){
    const float r = s + prd(b2, c, loW);
    if (*flag) ((float*)out)[z] = r;
    else       ((bf16*)out)[z] = __float2bfloat16(r);
  }
}

// =======================================================================
// Arena identical to round 8-10 (peak ~155 MiB, proven cap 167.3 MiB).
// =======================================================================
extern "C" void kernel_launch(void* const* d_in, const int* in_sizes, int n_in,
                              void* d_out, int out_size, void* d_ws, size_t ws_size,
                              hipStream_t stream) {
  const int* lengths = (const int*)d_in[2];
  char* ws = (char*)d_ws;
  const size_t KB = 1024;

  short* wtsH = (short*)ws;
  int* flag = (int*)(ws + 47500*KB);
  short* xxH = (short*)(ws + 48000*KB);
  const long loXX = 17301504;
  char* SC = ws + 115600*KB;

  short* hgA = (short*)(SC + 0*KB);      const long loHG = 2097152;
  short* hgB = (short*)(SC + 8192*KB);
  short* qkc = (short*)(SC + 16384*KB);  const long loQK1 = 4194304;
  short* VtS = (short*)(SC + 32768*KB);  const long loVT1 = 2097152;
  float* S0c = (float*)(SC + 40960*KB);
  float* S1c = (float*)(SC + 41984*KB);
  short* qkb = (short*)(SC + 0*KB);      const long loQK2 = 4325376;
  short* o_c = (short*)(SC + 0*KB);      const long loOC  = 2162688;
  short* pjb = (short*)(SC + 8448*KB);   const long loPJ  = 2162688;
  short* vtb = (short*)(SC + 16896*KB);  const long loVT2 = 2162688;
  float* att = (float*)(SC + 25344*KB);
  short* ff1 = (short*)(SC + 0*KB);      const long loFF  = 4194304;
  short* pj2 = (short*)(SC + 16896*KB);  const long loPJ2 = 4325376;
  short* pooled = (short*)(SC + 0*KB);   const long loPO  = 133120;
  short* hid    = (short*)(SC + 1024*KB);

  CvtTab tb; long cur = 0; int nb = 0; int e = 0;
  auto add = [&](int idx, long so, long n)->long{
    tb.src[e] = d_in[idx]; tb.srcOff[e] = so; tb.dstOff[e] = cur;
    tb.n[e] = (int)n; tb.bstart[e] = nb;
    nb += (int)((n + 255)/256); cur += n; e++;
    return cur - n;
  };
  const long oT  = add(1,0,32768);
  const long oSt = add(3,0,8192);
  const long oRu = add(4,0,512);
  const long oSW = add(5,0,32768);
  const long oSb = add(6,0,512);
  long oQKSV[2], oBQ[2];
  for (int l = 0; l < 2; ++l){
    oQKSV[l] = add(7, (long)l*1048576, 1048576);
    add(8,  (long)l*1048576, 1048576);
    add(13, (long)l*1048576, 1048576);
    add(9,  (long)l*1048576, 1048576);
  }
  for (int l = 0; l < 2; ++l){
    oBQ[l] = add(10, (long)l*1024, 1024);
    add(11, (long)l*1024, 1024);
    add(14, (long)l*1024, 1024);
    add(12, (long)l*1024, 1024);
  }
  const long oWqkv = add(15,0,1672704);
  const long obqkv = add(16,0,3168);
  const long oWo = add(17,0,557568);
  const long obo = add(18,0,1056);
  const long oW1 = add(19,0,135168);
  const long ob1 = add(20,0,256);
  const long oW2 = add(21,0,135168);
  const long ob2 = add(22,0,1056);
  const long og1 = add(23,0,1056);
  const long obb1 = add(24,0,1056);
  const long og2 = add(25,0,1056);
  const long obb2 = add(26,0,1056);
  const long oM1 = add(27,0,1081600);
  const long oM1b = add(28,0,1040);
  const long oM2 = add(29,0,2080);
  const long oM2b = add(30,0,2);
  tb.cnt = e;
  const long loW = (cur + 7) & ~7L;

  detect_k<<<1,256,0,stream>>>(d_in[0], flag);
  cvt_all<<<nb,256,0,stream>>>(tb, wtsH, loW, flag);

  const Route RZ{nullptr,0,0,0,0,0,0};

  // ================= stage 1: propagation (16-batch chunks) =================
  const int G1 = 16;
  for (int b0 = 0; b0 < B_; b0 += G1){
    build_hg<<<dim3(T_, G1), 128, 0, stream>>>(d_in[0], wtsH+oRu, loW, hgA, loHG, flag, b0);
    short* curb = hgA; short* nxtb = hgB;
    for (int l = 0; l < 2; ++l){
      float* S = (l == 0) ? S0c : S1c;
      {
        Route q{qkc, 2048, loQK1, 0, 0, 2048, 0};
        Route s{nxtb, 1024, loHG, 0, 0, 3072, 0};
        Route v{VtS, 2048, loVT1, 0, 0, 4096, 1};
        gemm_s<false,true><<<dim3(32,16,1),256,0,stream>>>(
            curb, loHG, wtsH+oQKSV[l], loW, wtsH+oBQ[l], loW,
            2048, 4096, 1024, 1024, 1024,
            1, 0,0,0,0, 0, 3, q, s, v, 1.f);
      }
      gemm_sm<128,true><<<dim3(1,1,G1),256,0,stream>>>(
          qkc, loQK1, qkc+1024, loQK1,
          1024, 2048, 2048,
          G1, 262144, 262144, 0, 0,
          S, 16384, 0, 128,
          0.03125f, nullptr, 0,
          (l == 1) ? S0c : nullptr, 16384);
      {
        Route c{nxtb, 1024, loHG, 131072, 0, 1024, 2};
        gemm_s<true,true><<<dim3(8,1,G1),256,0,stream>>>(
            S, 0, VtS, loVT1, nullptr, 0,
            128, 1024, 128, 128, 2048,
            G1, 16384, 128, 0, 0, 0, 1, c, RZ, RZ, 1.f);
      }
      short* t_ = curb; curb = nxtb; nxtb = t_;
    }
    build_xx<<<T_*G1,256,0,stream>>>(curb, loHG, wtsH+oT, loW, xxH, loXX, b0, G1);
  }

  // ================= stage 2: transformer (16-batch chunks) =================
  const float iscl = 1.0f / sqrtf((float)HD_);
  const int G2 = 16;
  for (int l = 0; l < 2; ++l){
    const long wqkv = oWqkv + (long)l*836352;
    const long bqkv = obqkv + (long)l*1584;
    for (int b0 = 0; b0 < B_; b0 += G2){
      {
        Route qk{qkb, 1056, loQK2, 270336, 0, 1056, 0};
        Route v{vtb, 256, loVT2, 135168, 0, 1584, 1};
        gemm_s<false,true><<<dim3(13,2,G2),256,0,stream>>>(
            xxH + (long)b0*D_MODEL_, loXX, wtsH+wqkv, loW, wtsH+bqkv, loW,
            256, 1584, 528, (long)B_*D_MODEL_, 528,
            G2, 528, 0, 0, 0, 0, 2, qk, v, RZ, 1.f);
      }
      gemm_sm<256,false><<<dim3(1,2,G2*NH_),256,0,stream>>>(
          qkb, loQK2, qkb+528, loQK2,
          132, 1056, 1056,
          G2, 270336, 270336, 132, 132,
          att, 262144, 65536, 256,
          iscl, lengths, b0, nullptr, 0);
      {
        Route c{o_c, 528, loOC, 135168, 132, HD_, 0};
        gemm_s<true,true><<<dim3(2,2,G2*NH_),256,0,stream>>>(
            att, 0, vtb, loVT2, nullptr, 0,
            256, HD_, 256, 256, 256,
            G2, 262144, 135168, 65536, 33792, 0, 1, c, RZ, RZ, 1.f);
      }
      {
        Route c{pjb, 528, loPJ, 135168, 0, 528, 0};
        gemm_s<false,true><<<dim3(5,2,G2),256,0,stream>>>(
            o_c, loOC, wtsH+oWo+(long)l*278784, loW, wtsH+obo+(long)l*528, loW,
            256, 528, 528, 528, 528,
            G2, 135168, 0, 0, 0, 0, 1, c, RZ, RZ, 1.f);
      }
      ln_res_attn<<<G2*256,256,0,stream>>>(xxH, loXX, pjb, loPJ,
          wtsH+og1+(long)l*528, wtsH+obb1+(long)l*528, loW, b0);
    }
    {
      Route c{ff1, 128, loFF, 0, 0, 128, 0};
      gemm_s<false,true><<<dim3(1,256,1),256,0,stream>>>(
          xxH, loXX, wtsH+oW1+(long)l*67584, loW, wtsH+ob1+(long)l*128, loW,
          32768, 128, 528, 528, 528,
          1, 0,0,0,0, 1, 1, c, RZ, RZ, 1.f);
    }
    for (int r0 = 0; r0 < 32768; r0 += 8192){
      Route c{pj2, 528, loPJ2, 0, 0, 528, 0};
      gemm_s<false,true><<<dim3(5,64,1),256,0,stream>>>(
          ff1 + (long)r0*128, loFF, wtsH+oW2+(long)l*67584, loW, wtsH+ob2+(long)l*528, loW,
          8192, 528, 128, 128, 128,
          1, 0,0,0,0, 0, 1, c, RZ, RZ, 1.f);
      ln_res_rows<<<8192,256,0,stream>>>(xxH, loXX, pj2, loPJ2,
          wtsH+og2+(long)l*528, wtsH+obb2+(long)l*528, loW, r0);
    }
  }

  // ================= stage 3: pool + MLP head =================
  pool_k<<<dim3(3,B_),256,0,stream>>>(xxH, loXX, lengths, pooled, loPO);
  {
    Route c{pooled + D_MODEL_, 1040, loPO, 0, 0, 512, 0};
    gemm_s<false,true><<<dim3(4,1,1),256,0,stream>>>(
        wtsH+oSt, loW, wtsH+oSW, loW, wtsH+oSb, loW,
        128, 512, 64, 64, 64,
        1, 0,0,0,0, 0, 1, c, RZ, RZ, 1.f);
  }
  {
    Route c{hid, 1040, loPO, 0, 0, 1040, 0};
    gemm_s<false,true><<<dim3(9,1,1),256,0,stream>>>(
        pooled, loPO, wtsH+oM1, loW, wtsH+oM1b, loW,
        128, 1040, 1040, 1040, 1040,
        1, 0,0,0,0, 1, 1, c, RZ, RZ, 1.f);
  }
  logits_k<<<B_*2,64,0,stream>>>(hid, loPO, wtsH+oM2, wtsH+oM2b, loW, d_out, flag);
}

// Round 12
// 6712.654 us; speedup vs baseline: 2.0473x; 1.0598x over previous
//
#include <hip/hip_runtime.h>
#include <hip/hip_bf16.h>
#include <math.h>

#define SE_    128
#define T_     256
#define B_     128
#define NH_    4
#define HD_    132
#define D_MODEL_ 528
#define D_FINAL_ 1040
#define D_FF_  128

typedef __hip_bfloat16 bf16;
typedef __attribute__((ext_vector_type(8))) short bf16x8v;
typedef __attribute__((ext_vector_type(4))) float f32x4;

__device__ __forceinline__ float bfb(unsigned short u){
  union { float f; unsigned int i; } c; c.i = ((unsigned int)u) << 16; return c.f;
}
__device__ __forceinline__ unsigned short bfr(float x){
  unsigned u = __builtin_bit_cast(unsigned, x);
  unsigned r = (u + 0x7FFFu + ((u >> 16) & 1u)) >> 16;
  return (unsigned short)r;
}
__device__ __forceinline__ void split1(float x, short& h, short& l){
  const unsigned short hu = bfr(x);
  const unsigned short lu = bfr(x - bfb(hu));
  h = (short)hu; l = (short)lu;
}
__device__ __forceinline__ float prd(const short* p, long i, long lo){
  return bfb((unsigned short)p[i]) + bfb((unsigned short)p[i+lo]);
}
__device__ __forceinline__ float rdIn(const void* p, long i, int f32){
  return f32 ? ((const float*)p)[i] : __bfloat162float(((const bf16*)p)[i]);
}

// ---------------- dtype detect: 1 = f32 inputs, 0 = bf16 ----------------
__global__ void detect_k(const void* __restrict__ src, int* __restrict__ flag){
  const unsigned int* p = (const unsigned int*)src;
  int bad = 0;
  for (int i = threadIdx.x; i < 4096; i += 256){
    const unsigned int lo = p[i] & 0xFFFFu;
    const unsigned int e = (lo >> 7) & 0xFFu;
    if (e >= 0xC0u) bad++;
  }
  __shared__ int red[256];
  red[threadIdx.x] = bad; __syncthreads();
  for (int h = 128; h > 0; h >>= 1){
    if (threadIdx.x < h) red[threadIdx.x] += red[threadIdx.x+h];
    __syncthreads();
  }
  if (threadIdx.x == 0) *flag = (red[0] > 64) ? 1 : 0;
}

// ---------------- mega conversion: 8 els/thread, int4 I/O ----------------
#define MAXE 40
struct CvtTab {
  const void* src[MAXE];
  long srcOff[MAXE];
  long dstOff[MAXE];
  int n[MAXE];
  int bstart[MAXE];
  int cnt;
};
__global__ void cvt_all(CvtTab tb, short* __restrict__ wts, long loW, const int* __restrict__ flag){
  const int b = blockIdx.x;
  int e = 0;
  for (int i = 1; i < tb.cnt; ++i) if (tb.bstart[i] <= b) e = i;
  const long n = tb.n[e];
  const long i0 = (long)(b - tb.bstart[e])*2048 + (long)threadIdx.x*8;
  if (i0 >= n) return;
  const int f32 = *flag;
  if (i0 + 8 <= n){
    short h8[8], l8[8];
    if (f32){
      const float* s = (const float*)tb.src[e] + tb.srcOff[e] + i0;
      float f[8];
      *(float4*)(f)   = *(const float4*)(s);
      *(float4*)(f+4) = *(const float4*)(s+4);
      #pragma unroll
      for (int k=0;k<8;++k) split1(f[k], h8[k], l8[k]);
    } else {
      const short* s = (const short*)tb.src[e] + tb.srcOff[e] + i0;
      *(int4*)h8 = *(const int4*)s;
      #pragma unroll
      for (int k=0;k<8;++k) l8[k] = 0;
    }
    *(int4*)(wts + tb.dstOff[e] + i0)       = *(const int4*)h8;
    *(int4*)(wts + tb.dstOff[e] + i0 + loW) = *(const int4*)l8;
  } else {
    for (long k = i0; k < n; ++k){
      const float v = rdIn(tb.src[e], tb.srcOff[e] + k, f32);
      short h, l; split1(v, h, l);
      wts[tb.dstOff[e] + k] = h;
      wts[tb.dstOff[e] + k + loW] = l;
    }
  }
}

// =======================================================================
// BK=64 swizzled LDS tiles: plane = short[128*64]. Row r, global K-chunk q
// (8 shorts): sub = q>>2, stored at chunk (q&3)^s(r) of sub, s(r)=(r&3)^((r>>2)&3).
// =======================================================================
__device__ __forceinline__ int swz(int r){ return (r&3) ^ ((r>>2)&3); }

// ---- DMA staging: 16 GLL insts/plane, 8 rows x 8 chunks each ----
__device__ __forceinline__ void gllstage_pair(const short* __restrict__ g, long lo, long ld,
    int kb, int row_g0, int rmax, int tid, short* Lh, short* Ll){
  const int w = tid>>6, ln = tid&63;
  #pragma unroll
  for (int inst=0; inst<4; ++inst){
    const int idx = w*4 + inst;                 // 0..15, 8 rows each
    const int r = idx*8 + (ln>>3);
    int gr = row_g0 + r; if (gr > rmax) gr = rmax;
    const int c = ln & 7;
    const int s = ((ln>>3)&3) ^ ((idx*2 + (ln>>5)) & 3);
    const int q = (c & 4) | ((c & 3) ^ s);
    const short* p = g + (long)gr*ld + kb + q*8;
    short* dh = Lh + idx*512;
    short* dl = Ll + idx*512;
    __builtin_amdgcn_global_load_lds(
        (const __attribute__((address_space(1))) void*)p,
        (__attribute__((address_space(3))) void*)dh, 16, 0, 0);
    __builtin_amdgcn_global_load_lds(
        (const __attribute__((address_space(1))) void*)(p + lo),
        (__attribute__((address_space(3))) void*)dl, 16, 0, 0);
  }
}

// ---- register staging (tails / unaligned), same layout ----
__device__ __forceinline__ void regstage_pair(const short* __restrict__ g, long lo, long ld,
    int kb, int K, int row_g0, int rmax, int tid, short* Lh, short* Ll){
  const int r = tid>>1;
  int gr = row_g0 + r; if (gr > rmax) gr = rmax;
  const int s = swz(r);
  #pragma unroll
  for (int cq=0;cq<4;++cq){
    const int q = (tid&1)*4 + cq;               // global chunk 0..7
    const int k0 = kb + q*8;
    short bh[8], bl[8];
    const short* p = g + (long)gr*ld + k0;
    if (k0 + 8 <= K){
      *(int2*)(bh)   = *(const int2*)(p);      *(int2*)(bh+4) = *(const int2*)(p+4);
      *(int2*)(bl)   = *(const int2*)(p+lo);   *(int2*)(bl+4) = *(const int2*)(p+lo+4);
    } else {
      #pragma unroll
      for (int e=0;e<8;++e){
        const bool ok = (k0+e) < K;
        bh[e] = ok ? p[e] : (short)0;
        bl[e] = ok ? p[lo+e] : (short)0;
      }
    }
    const int off = r*64 + (q>>2)*32 + ((q&3)^s)*8;
    *(int4*)&Lh[off] = *(const int4*)bh;
    *(int4*)&Ll[off] = *(const int4*)bl;
  }
}

__device__ __forceinline__ void regstage_f32(const float* __restrict__ g, long ld,
    int kb, int K, int row_g0, int rmax, int tid, short* Lh, short* Ll){
  const int r = tid>>1;
  int gr = row_g0 + r; if (gr > rmax) gr = rmax;
  const int s = swz(r);
  #pragma unroll
  for (int cq=0;cq<4;++cq){
    const int q = (tid&1)*4 + cq;
    const int k0 = kb + q*8;
    short bh[8], bl[8];
    const float* p = g + (long)gr*ld + k0;
    if (k0 + 8 <= K){
      float f[8];
      *(float4*)(f)   = *(const float4*)(p);
      *(float4*)(f+4) = *(const float4*)(p+4);
      #pragma unroll
      for (int e=0;e<8;++e) split1(f[e], bh[e], bl[e]);
    } else {
      #pragma unroll
      for (int e=0;e<8;++e){
        const float v = (k0+e < K) ? p[e] : 0.f;
        split1(v, bh[e], bl[e]);
      }
    }
    const int off = r*64 + (q>>2)*32 + ((q&3)^s)*8;
    *(int4*)&Lh[off] = *(const int4*)bh;
    *(int4*)&Ll[off] = *(const int4*)bl;
  }
}

// ---- swizzled frag read, sub-iteration si in {0,1} ----
__device__ __forceinline__ void rd_frags(const short* Lh, const short* Ll,
                                         int wbase, int fr, int qlog, int si,
                                         bf16x8v ah[4], bf16x8v al[4]){
  const int cs = si*32 + ((qlog ^ ((fr&3) ^ ((fr>>2)&3)))) * 8;
  #pragma unroll
  for (int i=0;i<4;++i){
    const int r_ = wbase + i*16 + fr;
    ah[i] = *reinterpret_cast<const bf16x8v*>(&Lh[r_*64 + cs]);
    al[i] = *reinterpret_cast<const bf16x8v*>(&Ll[r_*64 + cs]);
  }
}

// =======================================================================
// bf16x3 emulated-f32 NT GEMM: BK=64 LDS tiles via GLL DMA, routed epilogue.
// =======================================================================
struct Route { short* C; long ldc; long lo; long sC; long sC2; int nEnd; int fl; }; // fl: 1=trans 2=acc

template<bool SPLITA, bool GLL>
__global__ __launch_bounds__(256, 2) void gemm_s(
    const void* __restrict__ Ag, long loA,
    const short* __restrict__ Bg, long loB,
    const short* __restrict__ bias, long loBias,
    int M, int N, int K, long lda, long ldb,
    int nz1, long sA, long sB, long sA2, long sB2,
    int relu, int nroute, Route r0, Route r1, Route r2, float mult)
{
  __shared__ short As_h[128*64], As_l[128*64], Bs_h[128*64], Bs_l[128*64];
  const int tid = threadIdx.x;
  const int z1 = blockIdx.z % nz1, z2 = blockIdx.z / nz1;
  const int m0 = blockIdx.y*128, n0 = blockIdx.x*128;
  const void* A;
  if (SPLITA) A = (const void*)((const float*)Ag + z1*sA + z2*sA2);
  else        A = (const void*)((const short*)Ag + z1*sA + z2*sA2);
  const short* B = Bg + z1*sB + z2*sB2;
  short* Cb0 = r0.C + z1*r0.sC + z2*r0.sC2;
  short* Cb1 = (nroute > 1) ? (r1.C + z1*r1.sC + z2*r1.sC2) : nullptr;
  short* Cb2 = (nroute > 2) ? (r2.C + z1*r2.sC + z2*r2.sC2) : nullptr;

  const int lane = tid & 63, wv = tid >> 6;
  const int wm = (wv >> 1)*64, wn = (wv & 1)*64;
  const int fr = lane & 15, qlog = lane >> 4;

  f32x4 acc[4][4] = {};
  for (int kb = 0; kb < K; kb += 64){
    const bool tail = (kb + 64 > K);
    if (SPLITA) regstage_f32((const float*)A, lda, kb, K, m0, M-1, tid, As_h, As_l);
    else if (GLL && !tail) gllstage_pair((const short*)A, loA, lda, kb, m0, M-1, tid, As_h, As_l);
    else regstage_pair((const short*)A, loA, lda, kb, K, m0, M-1, tid, As_h, As_l);
    if (GLL && !tail) gllstage_pair(B, loB, ldb, kb, n0, N-1, tid, Bs_h, Bs_l);
    else regstage_pair(B, loB, ldb, kb, K, n0, N-1, tid, Bs_h, Bs_l);
    __syncthreads();

    #pragma unroll
    for (int si=0; si<2; ++si){
      bf16x8v ah[4], al[4], bh[4], bl[4];
      rd_frags(As_h, As_l, wm, fr, qlog, si, ah, al);
      rd_frags(Bs_h, Bs_l, wn, fr, qlog, si, bh, bl);
      #pragma unroll
      for (int j=0;j<4;++j)
        #pragma unroll
        for (int i=0;i<4;++i){
          acc[i][j] = __builtin_amdgcn_mfma_f32_16x16x32_bf16(ah[i], bh[j], acc[i][j], 0,0,0);
          acc[i][j] = __builtin_amdgcn_mfma_f32_16x16x32_bf16(ah[i], bl[j], acc[i][j], 0,0,0);
          acc[i][j] = __builtin_amdgcn_mfma_f32_16x16x32_bf16(al[i], bh[j], acc[i][j], 0,0,0);
        }
    }
    __syncthreads();
  }

  const int cr = (lane >> 4)*4, cc = lane & 15;
  #pragma unroll
  for (int i=0;i<4;++i){
    #pragma unroll
    for (int j=0;j<4;++j){
      #pragma unroll
      for (int rr=0;rr<4;++rr){
        const int gm = m0 + wm + i*16 + cr + rr;
        const int gn = n0 + wn + j*16 + cc;
        if (gm < M && gn < N){
          float v = acc[i][j][rr] * mult;
          if (bias) v += prd(bias, gn, loBias);
          if (relu) v = fmaxf(v, 0.f);
          short* Cp; long ldc, lo; int fl, cn;
          if (nroute > 1 && gn >= r0.nEnd){
            if (nroute > 2 && gn >= r1.nEnd){ Cp=Cb2; ldc=r2.ldc; lo=r2.lo; fl=r2.fl; cn=gn-r1.nEnd; }
            else                            { Cp=Cb1; ldc=r1.ldc; lo=r1.lo; fl=r1.fl; cn=gn-r0.nEnd; }
          } else                            { Cp=Cb0; ldc=r0.ldc; lo=r0.lo; fl=r0.fl; cn=gn; }
          const long idx = (fl & 1) ? ((long)cn*ldc + gm) : ((long)gm*ldc + cn);
          if (fl & 2) v += prd(Cp, idx, lo);
          short h, l; split1(v, h, l);
          Cp[idx] = h; Cp[idx + lo] = l;
        }
      }
    }
  }
}

// =======================================================================
// scores GEMM (BK=64) + fused wave-parallel row softmax.
// =======================================================================
template<int NN, bool GLL>
__global__ __launch_bounds__(256, 2) void gemm_sm(
    const short* __restrict__ Ag, long loA, const short* __restrict__ Bg, long loB,
    int K, long lda, long ldb,
    int nz1, long sA, long sB, long sA2, long sB2,
    float* __restrict__ Sg, long sS, long sS2, int ldS,
    float mult, const int* __restrict__ lengths, int b0,
    const float* __restrict__ mulP, long sMul)
{
  __shared__ short As_h[128*64], As_l[128*64], Bs_h[128*64], Bs_l[128*64];
  const int tid = threadIdx.x;
  const int z1 = blockIdx.z % nz1, z2 = blockIdx.z / nz1;
  const int m0 = blockIdx.y*128;
  const short* A = Ag + z1*sA + z2*sA2;
  const short* B = Bg + z1*sB + z2*sB2;
  float* S = Sg + z1*sS + z2*sS2;

  const int lane = tid & 63, wv = tid >> 6;
  const int wm = (wv >> 1)*64, wn = (wv & 1)*64;
  const int fr = lane & 15, qlog = lane >> 4;
  const int cr = (lane >> 4)*4, cc = lane & 15;

  for (int nh = 0; nh < NN; nh += 128){
    f32x4 acc[4][4] = {};
    for (int kb = 0; kb < K; kb += 64){
      const bool tail = (kb + 64 > K);
      if (GLL && !tail){
        gllstage_pair(A, loA, lda, kb, m0, m0+127, tid, As_h, As_l);
        gllstage_pair(B, loB, ldb, kb, nh, nh+127, tid, Bs_h, Bs_l);
      } else {
        regstage_pair(A, loA, lda, kb, K, m0, m0+127, tid, As_h, As_l);
        regstage_pair(B, loB, ldb, kb, K, nh, nh+127, tid, Bs_h, Bs_l);
      }
      __syncthreads();
      #pragma unroll
      for (int si=0; si<2; ++si){
        bf16x8v ah[4], al[4], bh[4], bl[4];
        rd_frags(As_h, As_l, wm, fr, qlog, si, ah, al);
        rd_frags(Bs_h, Bs_l, wn, fr, qlog, si, bh, bl);
        #pragma unroll
        for (int j=0;j<4;++j)
          #pragma unroll
          for (int i=0;i<4;++i){
            acc[i][j] = __builtin_amdgcn_mfma_f32_16x16x32_bf16(ah[i], bh[j], acc[i][j], 0,0,0);
            acc[i][j] = __builtin_amdgcn_mfma_f32_16x16x32_bf16(ah[i], bl[j], acc[i][j], 0,0,0);
            acc[i][j] = __builtin_amdgcn_mfma_f32_16x16x32_bf16(al[i], bh[j], acc[i][j], 0,0,0);
          }
      }
      __syncthreads();
    }
    #pragma unroll
    for (int i=0;i<4;++i)
      #pragma unroll
      for (int j=0;j<4;++j)
        #pragma unroll
        for (int rr=0;rr<4;++rr){
          const int gm = m0 + wm + i*16 + cr + rr;
          const int gn = nh + wn + j*16 + cc;
          S[(long)gm*ldS + gn] = acc[i][j][rr] * mult;
        }
  }
  __syncthreads();   // S fully written, block-visible

  // ---- wave-parallel row softmax: wave wv owns rows m0+wv*32 .. +31 ----
  constexpr int CH = NN / 64;               // cols per lane: 2 or 4
  const int cbase = lane*CH;
  int lim = NN;
  if (lengths){ const int L = lengths[b0 + z1]; lim = (L < NN) ? L : NN; }

  float v[CH], vn[CH], mcur[CH], mnxt[CH];
  {
    float* row0 = S + (long)(m0 + wv*32)*ldS + cbase;
    #pragma unroll
    for (int e=0;e<CH;++e) v[e] = row0[e];
    if (mulP){
      const float* mr = mulP + z1*sMul + (long)(m0 + wv*32)*ldS + cbase;
      #pragma unroll
      for (int e=0;e<CH;++e) mcur[e] = mr[e];
    }
  }
  for (int i = 0; i < 32; ++i){
    if (i < 31){
      float* rn = S + (long)(m0 + wv*32 + i + 1)*ldS + cbase;
      #pragma unroll
      for (int e=0;e<CH;++e) vn[e] = rn[e];
      if (mulP){
        const float* mr = mulP + z1*sMul + (long)(m0 + wv*32 + i + 1)*ldS + cbase;
        #pragma unroll
        for (int e=0;e<CH;++e) mnxt[e] = mr[e];
      }
    }
    float mx = -3.0e38f;
    #pragma unroll
    for (int e=0;e<CH;++e) if (cbase+e < lim) mx = fmaxf(mx, v[e]);
    #pragma unroll
    for (int o=32;o>0;o>>=1) mx = fmaxf(mx, __shfl_xor(mx, o, 64));
    float sm = 0.f;
    #pragma unroll
    for (int e=0;e<CH;++e){
      v[e] = (cbase+e < lim) ? __expf(v[e] - mx) : 0.f;
      sm += v[e];
    }
    #pragma unroll
    for (int o=32;o>0;o>>=1) sm += __shfl_xor(sm, o, 64);
    const float inv = 1.f / sm;
    float* row = S + (long)(m0 + wv*32 + i)*ldS + cbase;
    if (mulP){
      #pragma unroll
      for (int e=0;e<CH;++e) row[e] = v[e]*inv*mcur[e];
    } else {
      #pragma unroll
      for (int e=0;e<CH;++e) row[e] = v[e]*inv;
    }
    #pragma unroll
    for (int e=0;e<CH;++e){ v[e] = vn[e]; mcur[e] = mnxt[e]; }
  }
}

// ---------------- hg chunk init (pair out) ----------------
__global__ void build_hg(const void* __restrict__ src, const short* __restrict__ Ru, long loW,
                         short* __restrict__ hg, long loH, const int* __restrict__ flag, int b0){
  const int t = blockIdx.x, bl = blockIdx.y, se = threadIdx.x;  // block 128
  const int f32 = *flag;
  const float s = rdIn(src, ((long)t*B_ + (b0+bl))*(2*SE_) + se, f32);
  const long o = ((long)bl*SE_ + se)*1024 + t*4;
  #pragma unroll
  for (int j=0;j<4;++j){
    const float v = fmaxf(s * prd(Ru, se*4+j, loW), 0.f);
    short h, l; split1(v, h, l);
    hg[o+j] = h; hg[o+j+loH] = l;
  }
}

// ---------------- xx chunk build (pair in/out) ----------------
__global__ void build_xx(const short* __restrict__ hg, long loH,
                         const short* __restrict__ times, long loW,
                         short* __restrict__ xx, long loX, int b0, int G){
  const int blk = blockIdx.x;          // t*G + bl
  const int t = blk / G, bl = blk % G, b = b0 + bl;
  const int tid = threadIdx.x;
  const float tm = prd(times, (long)t*B_ + b, loW);
  for (int c = tid; c < D_MODEL_; c += 256){
    float v;
    if (c < SE_*4){
      v = prd(hg, ((long)bl*SE_ + (c>>2))*1024 + t*4 + (c&3), loH);
    } else {
      const int p = c - SE_*4;
      const int i = p & 7;
      const float ts = exp2f(8.0f * (float)i / 7.0f);
      const float st = tm / ts;
      v = (p < 8) ? sinf(st) : cosf(st);
    }
    short h, l; split1(v, h, l);
    const long o = ((long)t*B_ + b)*D_MODEL_ + c;
    xx[o] = h; xx[o+loX] = l;
  }
}

// ---------------- LN body (row = 528, pairs) ----------------
__device__ __forceinline__ void ln_body_p(short* px, long loX, const short* pr, long loR,
                                          const short* g, const short* bb, long loW, int tid){
  const float x0 = prd(px,tid,loX)     + prd(pr,tid,loR);
  const float x1 = prd(px,tid+256,loX) + prd(pr,tid+256,loR);
  const float x2 = (tid < 16) ? (prd(px,tid+512,loX) + prd(pr,tid+512,loR)) : 0.f;
  __shared__ float rs[256], rq[256];
  rs[tid] = x0 + x1 + x2;
  rq[tid] = x0*x0 + x1*x1 + x2*x2;
  __syncthreads();
  for (int h = 128; h > 0; h >>= 1){
    if (tid < h){ rs[tid] += rs[tid+h]; rq[tid] += rq[tid+h]; }
    __syncthreads();
  }
  const float mean = rs[0] * (1.0f/528.0f);
  const float var  = rq[0] * (1.0f/528.0f) - mean*mean;
  const float inv = rsqrtf(var + 1e-5f);
  short h, l;
  split1((x0-mean)*inv*prd(g,tid,loW) + prd(bb,tid,loW), h, l);
  px[tid] = h; px[tid+loX] = l;
  split1((x1-mean)*inv*prd(g,tid+256,loW) + prd(bb,tid+256,loW), h, l);
  px[tid+256] = h; px[tid+256+loX] = l;
  if (tid < 16){
    split1((x2-mean)*inv*prd(g,tid+512,loW) + prd(bb,tid+512,loW), h, l);
    px[tid+512] = h; px[tid+512+loX] = l;
  }
}

__global__ __launch_bounds__(256) void ln_res_attn(short* __restrict__ xx, long loX,
    const short* __restrict__ res, long loR,
    const short* __restrict__ g, const short* __restrict__ bb, long loW, int b0){
  const int z = blockIdx.x >> 8, t = blockIdx.x & 255;
  short* px = xx + ((long)t*B_ + b0 + z)*D_MODEL_;
  const short* pr = res + (long)blockIdx.x*D_MODEL_;
  ln_body_p(px, loX, pr, loR, g, bb, loW, threadIdx.x);
}

__global__ __launch_bounds__(256) void ln_res_rows(short* __restrict__ xx, long loX,
    const short* __restrict__ res, long loR,
    const short* __restrict__ g, const short* __restrict__ bb, long loW, int r0){
  short* px = xx + ((long)r0 + blockIdx.x)*D_MODEL_;
  const short* pr = res + (long)blockIdx.x*D_MODEL_;
  ln_body_p(px, loX, pr, loR, g, bb, loW, threadIdx.x);
}

// ---------------- masked mean pool (pair in/out) ----------------
__global__ void pool_k(const short* __restrict__ xx, long loX, const int* __restrict__ len,
                       short* __restrict__ pooled, long loP){
  const int b = blockIdx.y;
  const int c = blockIdx.x*256 + threadIdx.x;
  if (c >= D_MODEL_) return;
  const int L = len[b];
  float s = 0.f;
  for (int t = 0; t < L; ++t) s += prd(xx, ((long)t*B_ + b)*D_MODEL_ + c, loX);
  short h, l; split1(s / (float)(L + 1), h, l);
  pooled[(long)b*D_FINAL_ + c] = h;
  pooled[(long)b*D_FINAL_ + c + loP] = l;
}

// ---------------- logits (pair in, out dtype per flag) ----------------
__global__ void logits_k(const short* __restrict__ hid, long loH,
                         const short* __restrict__ W2, const short* __restrict__ b2, long loW,
                         void* __restrict__ out, const int* __restrict__ flag){
  const int z = blockIdx.x;            // b*2 + c
  const int b = z >> 1, c = z & 1;
  const int lane = threadIdx.x;        // 64
  float s = 0.f;
  for (int k = lane; k < D_FINAL_; k += 64)
    s += prd(hid, (long)b*D_FINAL_ + k, loH) * prd(W2, (long)c*D_FINAL_ + k, loW);
  #pragma unroll
  for (int o = 32; o > 0; o >>= 1) s += __shfl_down(s, o, 64);
  if (lane == 0){
    const float r = s + prd(b2, c, loW);
    if (*flag) ((float*)out)[z] = r;
    else       ((bf16*)out)[z] = __float2bfloat16(r);
  }
}

// =======================================================================
// Arena identical to rounds 8-11 (peak ~155 MiB, proven cap 167.3 MiB).
// =======================================================================
extern "C" void kernel_launch(void* const* d_in, const int* in_sizes, int n_in,
                              void* d_out, int out_size, void* d_ws, size_t ws_size,
                              hipStream_t stream) {
  const int* lengths = (const int*)d_in[2];
  char* ws = (char*)d_ws;
  const size_t KB = 1024;

  short* wtsH = (short*)ws;
  int* flag = (int*)(ws + 47500*KB);
  short* xxH = (short*)(ws + 48000*KB);
  const long loXX = 17301504;
  char* SC = ws + 115600*KB;

  short* hgA = (short*)(SC + 0*KB);      const long loHG = 2097152;
  short* hgB = (short*)(SC + 8192*KB);
  short* qkc = (short*)(SC + 16384*KB);  const long loQK1 = 4194304;
  short* VtS = (short*)(SC + 32768*KB);  const long loVT1 = 2097152;
  float* S0c = (float*)(SC + 40960*KB);
  float* S1c = (float*)(SC + 41984*KB);
  short* qkb = (short*)(SC + 0*KB);      const long loQK2 = 4325376;
  short* o_c = (short*)(SC + 0*KB);      const long loOC  = 2162688;
  short* pjb = (short*)(SC + 8448*KB);   const long loPJ  = 2162688;
  short* vtb = (short*)(SC + 16896*KB);  const long loVT2 = 2162688;
  float* att = (float*)(SC + 25344*KB);
  short* ff1 = (short*)(SC + 0*KB);      const long loFF  = 4194304;
  short* pj2 = (short*)(SC + 16896*KB);  const long loPJ2 = 4325376;
  short* pooled = (short*)(SC + 0*KB);   const long loPO  = 133120;
  short* hid    = (short*)(SC + 1024*KB);

  CvtTab tb; long cur = 0; int nb = 0; int e = 0;
  auto add = [&](int idx, long so, long n)->long{
    tb.src[e] = d_in[idx]; tb.srcOff[e] = so; tb.dstOff[e] = cur;
    tb.n[e] = (int)n; tb.bstart[e] = nb;
    nb += (int)((n + 2047)/2048); cur += n; e++;
    return cur - n;
  };
  const long oT  = add(1,0,32768);
  const long oSt = add(3,0,8192);
  const long oRu = add(4,0,512);
  const long oSW = add(5,0,32768);
  const long oSb = add(6,0,512);
  long oQKSV[2], oBQ[2];
  for (int l = 0; l < 2; ++l){
    oQKSV[l] = add(7, (long)l*1048576, 1048576);
    add(8,  (long)l*1048576, 1048576);
    add(13, (long)l*1048576, 1048576);
    add(9,  (long)l*1048576, 1048576);
  }
  for (int l = 0; l < 2; ++l){
    oBQ[l] = add(10, (long)l*1024, 1024);
    add(11, (long)l*1024, 1024);
    add(14, (long)l*1024, 1024);
    add(12, (long)l*1024, 1024);
  }
  const long oWqkv = add(15,0,1672704);
  const long obqkv = add(16,0,3168);
  const long oWo = add(17,0,557568);
  const long obo = add(18,0,1056);
  const long oW1 = add(19,0,135168);
  const long ob1 = add(20,0,256);
  const long oW2 = add(21,0,135168);
  const long ob2 = add(22,0,1056);
  const long og1 = add(23,0,1056);
  const long obb1 = add(24,0,1056);
  const long og2 = add(25,0,1056);
  const long obb2 = add(26,0,1056);
  const long oM1 = add(27,0,1081600);
  const long oM1b = add(28,0,1040);
  const long oM2 = add(29,0,2080);
  const long oM2b = add(30,0,2);
  tb.cnt = e;
  const long loW = (cur + 7) & ~7L;

  detect_k<<<1,256,0,stream>>>(d_in[0], flag);
  cvt_all<<<nb,256,0,stream>>>(tb, wtsH, loW, flag);

  const Route RZ{nullptr,0,0,0,0,0,0};

  // ================= stage 1: propagation (16-batch chunks) =================
  const int G1 = 16;
  for (int b0 = 0; b0 < B_; b0 += G1){
    build_hg<<<dim3(T_, G1), 128, 0, stream>>>(d_in[0], wtsH+oRu, loW, hgA, loHG, flag, b0);
    short* curb = hgA; short* nxtb = hgB;
    for (int l = 0; l < 2; ++l){
      float* S = (l == 0) ? S0c : S1c;
      {
        Route q{qkc, 2048, loQK1, 0, 0, 2048, 0};
        Route s{nxtb, 1024, loHG, 0, 0, 3072, 0};
        Route v{VtS, 2048, loVT1, 0, 0, 4096, 1};
        gemm_s<false,true><<<dim3(32,16,1),256,0,stream>>>(
            curb, loHG, wtsH+oQKSV[l], loW, wtsH+oBQ[l], loW,
            2048, 4096, 1024, 1024, 1024,
            1, 0,0,0,0, 0, 3, q, s, v, 1.f);
      }
      gemm_sm<128,true><<<dim3(1,1,G1),256,0,stream>>>(
          qkc, loQK1, qkc+1024, loQK1,
          1024, 2048, 2048,
          G1, 262144, 262144, 0, 0,
          S, 16384, 0, 128,
          0.03125f, nullptr, 0,
          (l == 1) ? S0c : nullptr, 16384);
      {
        Route c{nxtb, 1024, loHG, 131072, 0, 1024, 2};
        gemm_s<true,true><<<dim3(8,1,G1),256,0,stream>>>(
            S, 0, VtS, loVT1, nullptr, 0,
            128, 1024, 128, 128, 2048,
            G1, 16384, 128, 0, 0, 0, 1, c, RZ, RZ, 1.f);
      }
      short* t_ = curb; curb = nxtb; nxtb = t_;
    }
    build_xx<<<T_*G1,256,0,stream>>>(curb, loHG, wtsH+oT, loW, xxH, loXX, b0, G1);
  }

  // ================= stage 2: transformer (16-batch chunks) =================
  const float iscl = 1.0f / sqrtf((float)HD_);
  const int G2 = 16;
  for (int l = 0; l < 2; ++l){
    const long wqkv = oWqkv + (long)l*836352;
    const long bqkv = obqkv + (long)l*1584;
    for (int b0 = 0; b0 < B_; b0 += G2){
      {
        Route qk{qkb, 1056, loQK2, 270336, 0, 1056, 0};
        Route v{vtb, 256, loVT2, 135168, 0, 1584, 1};
        gemm_s<false,true><<<dim3(13,2,G2),256,0,stream>>>(
            xxH + (long)b0*D_MODEL_, loXX, wtsH+wqkv, loW, wtsH+bqkv, loW,
            256, 1584, 528, (long)B_*D_MODEL_, 528,
            G2, 528, 0, 0, 0, 0, 2, qk, v, RZ, 1.f);
      }
      gemm_sm<256,false><<<dim3(1,2,G2*NH_),256,0,stream>>>(
          qkb, loQK2, qkb+528, loQK2,
          132, 1056, 1056,
          G2, 270336, 270336, 132, 132,
          att, 262144, 65536, 256,
          iscl, lengths, b0, nullptr, 0);
      {
        Route c{o_c, 528, loOC, 135168, 132, HD_, 0};
        gemm_s<true,true><<<dim3(2,2,G2*NH_),256,0,stream>>>(
            att, 0, vtb, loVT2, nullptr, 0,
            256, HD_, 256, 256, 256,
            G2, 262144, 135168, 65536, 33792, 0, 1, c, RZ, RZ, 1.f);
      }
      {
        Route c{pjb, 528, loPJ, 135168, 0, 528, 0};
        gemm_s<false,true><<<dim3(5,2,G2),256,0,stream>>>(
            o_c, loOC, wtsH+oWo+(long)l*278784, loW, wtsH+obo+(long)l*528, loW,
            256, 528, 528, 528, 528,
            G2, 135168, 0, 0, 0, 0, 1, c, RZ, RZ, 1.f);
      }
      ln_res_attn<<<G2*256,256,0,stream>>>(xxH, loXX, pjb, loPJ,
          wtsH+og1+(long)l*528, wtsH+obb1+(long)l*528, loW, b0);
    }
    {
      Route c{ff1, 128, loFF, 0, 0, 128, 0};
      gemm_s<false,true><<<dim3(1,256,1),256,0,stream>>>(
          xxH, loXX, wtsH+oW1+(long)l*67584, loW, wtsH+ob1+(long)l*128, loW,
          32768, 128, 528, 528, 528,
          1, 0,0,0,0, 1, 1, c, RZ, RZ, 1.f);
    }
    for (int r0 = 0; r0 < 32768; r0 += 8192){
      Route c{pj2, 528, loPJ2, 0, 0, 528, 0};
      gemm_s<false,true><<<dim3(5,64,1),256,0,stream>>>(
          ff1 + (long)r0*128, loFF, wtsH+oW2+(long)l*67584, loW, wtsH+ob2+(long)l*528, loW,
          8192, 528, 128, 128, 128,
          1, 0,0,0,0, 0, 1, c, RZ, RZ, 1.f);
      ln_res_rows<<<8192,256,0,stream>>>(xxH, loXX, pj2, loPJ2,
          wtsH+og2+(long)l*528, wtsH+obb2+(long)l*528, loW, r0);
    }
  }

  // ================= stage 3: pool + MLP head =================
  pool_k<<<dim3(3,B_),256,0,stream>>>(xxH, loXX, lengths, pooled, loPO);
  {
    Route c{pooled + D_MODEL_, 1040, loPO, 0, 0, 512, 0};
    gemm_s<false,true><<<dim3(4,1,1),256,0,stream>>>(
        wtsH+oSt, loW, wtsH+oSW, loW, wtsH+oSb, loW,
        128, 512, 64, 64, 64,
        1, 0,0,0,0, 0, 1, c, RZ, RZ, 1.f);
  }
  {
    Route c{hid, 1040, loPO, 0, 0, 1040, 0};
    gemm_s<false,true><<<dim3(9,1,1),256,0,stream>>>(
        pooled, loPO, wtsH+oM1, loW, wtsH+oM1b, loW,
        128, 1040, 1040, 1040, 1040,
        1, 0,0,0,0, 1, 1, c, RZ, RZ, 1.f);
  }
  logits_k<<<B_*2,64,0,stream>>>(hid, loPO, wtsH+oM2, wtsH+oM2b, loW, d_out, flag);
}